// Round 5
// baseline (950.185 us; speedup 1.0000x reference)
//
#include <hip/hip_runtime.h>

typedef unsigned short u16;
typedef unsigned int u32;
typedef __attribute__((ext_vector_type(8))) short bf16x8;
typedef __attribute__((ext_vector_type(4))) float f32x4;

static __device__ __forceinline__ float bf2f(u16 u) {
  union { unsigned int i; float f; } v; v.i = ((unsigned int)u) << 16; return v.f;
}
static __device__ __forceinline__ u16 f2bf(float f) {
  union { float f; unsigned int i; } v; v.f = f;
  unsigned int i = v.i;
  return (u16)((i + 0x7FFFu + ((i >> 16) & 1u)) >> 16);
}

// async global->LDS, 16B per lane (guide §5: width=16 is the fast path)
static __device__ __forceinline__ void gl16(const u16* g, u16* l) {
  __builtin_amdgcn_global_load_lds(
      (const __attribute__((address_space(1))) unsigned int*)g,
      (__attribute__((address_space(3))) unsigned int*)l, 16, 0, 0);
}

// counted vmcnt with literal immediate (asm requires literals)
template<int N> static __device__ __forceinline__ void vwait() {
  if constexpr (N == 0)       asm volatile("s_waitcnt vmcnt(0)" ::: "memory");
  else if constexpr (N == 6)  asm volatile("s_waitcnt vmcnt(6)" ::: "memory");
  else if constexpr (N == 8)  asm volatile("s_waitcnt vmcnt(8)" ::: "memory");
  else if constexpr (N == 10) asm volatile("s_waitcnt vmcnt(10)" ::: "memory");
  else if constexpr (N == 12) asm volatile("s_waitcnt vmcnt(12)" ::: "memory");
  else if constexpr (N == 14) asm volatile("s_waitcnt vmcnt(14)" ::: "memory");
  else                        asm volatile("s_waitcnt vmcnt(0)" ::: "memory");
}

// ---- convert f32 -> bf16 for both inputs in one launch ----
__global__ __launch_bounds__(256) void cvt2(const float* __restrict__ a, const float* __restrict__ b,
                                            u16* __restrict__ da, u16* __restrict__ db,
                                            int n4a, int n4b)
{
  int i = blockIdx.x * 256 + threadIdx.x;
  const float* s; u16* d; int j;
  if (i < n4a) { s = a; d = da; j = i; }
  else { j = i - n4a; if (j >= n4b) return; s = b; d = db; }
  float4 v = ((const float4*)s)[j];
  ushort4 r;
  r.x = f2bf(v.x); r.y = f2bf(v.y); r.z = f2bf(v.z); r.w = f2bf(v.w);
  ((ushort4*)d)[j] = r;
}

// ---- transpose R chunks: dst[r][n*K+k] (bf16) = src[r][k*N+n] (f32) ----
__global__ __launch_bounds__(256) void transpose3(const float* __restrict__ src,
                                                  u16* __restrict__ dst, int R, int K, int N)
{
  int idx = blockIdx.x * 256 + threadIdx.x;
  if (idx >= R * K * N) return;
  int r = idx / (K * N), rem = idx - r * K * N;
  int k = rem / N, n = rem - k * N;
  dst[(size_t)r * N * K + (size_t)n * K + k] = f2bf(src[idx]);
}

// ---- wr for two relations of one layer in one launch ----
__global__ __launch_bounds__(256) void build_wr2(
    const float* __restrict__ Wa, const float* __restrict__ Wb,
    const float* __restrict__ ara, const float* __restrict__ arb,
    float* __restrict__ wra, float* __restrict__ wrb, int K)
{
  int idx = blockIdx.x * 256 + threadIdx.x;
  if (idx >= 2 * K * 4) return;
  int sel = idx / (K * 4), rem = idx - sel * K * 4;
  int k = rem >> 2, h = rem & 3;
  const float* W = sel ? Wb : Wa;
  const float* ar = sel ? arb : ara;
  float s = 0.f;
  for (int d = 0; d < 64; ++d)
    s += W[(size_t)k * 256 + h * 64 + d] * ar[h * 64 + d];
  (sel ? wrb : wra)[rem] = s;
}

// ---- fully-resident-A GEMM: all NS K-stages staged in prologue (8-32KB LDS),
// no LDS reuse -> one barrier per K-step; B double-buffered 2 steps ahead;
// counted vmcnt from exact per-thread FIFO. MFMA order identical to prior
// version -> bit-identical results. ----
template<int K, int NTW>
__global__ __launch_bounds__(256, 3) void gemm_rb(
    const u16* __restrict__ X, const u16* __restrict__ Wt,
    u16* __restrict__ out16, float* __restrict__ out32,
    const float* __restrict__ bias,
    const float* __restrict__ al4, const float* __restrict__ ar4,
    float* __restrict__ el, float* __restrict__ er, int M)
{
  constexpr int NS = K / 64;                 // 64-wide K stages (2 or 4)
  constexpr int LB = 2 * NTW;                // vmem ops per load_b
  const int N = NTW * 16 * 4;
  __shared__ __align__(16) u16 As[NS][64 * 64];   // NS x 8KB, never overwritten
  const int t = threadIdx.x;
  const int wave = t >> 6, lane = t & 63;
  const int quad = lane >> 4, l16 = lane & 15;
  const int mbase = blockIdx.x * 64;
  const int nbase = wave * (NTW * 16);

  // staging: thread t covers rows r0 (round 0) and r1 (round 1), 16B each.
  // physical chunk = t&7; source chunk = (t&7) ^ (row&7)  (XOR involution)
  int r0 = t >> 3, r1 = 32 + (t >> 3);
  int c0 = (t & 7) ^ (r0 & 7);
  int c1 = (t & 7) ^ (r1 & 7);
  int rr0 = mbase + r0; if (rr0 >= M) rr0 = M - 1;   // clamp tail (stores guarded)
  int rr1 = mbase + r1; if (rr1 >= M) rr1 = M - 1;
  const u16* g0 = X + (size_t)rr0 * K + c0 * 8;
  const u16* g1 = X + (size_t)rr1 * K + c1 * 8;

  const u16* wp = Wt + (size_t)(nbase + l16) * K + quad * 8;

  f32x4 acc[4][NTW];
#pragma unroll
  for (int mt = 0; mt < 4; ++mt)
#pragma unroll
    for (int nt = 0; nt < NTW; ++nt) acc[mt][nt] = (f32x4){0.f, 0.f, 0.f, 0.f};

  bf16x8 bb[2][2][NTW];                      // two B stages, ping-pong on ks&1

  auto stage_a = [&](int s) {
    gl16(g0 + s * 64, &As[s][t * 8]);
    gl16(g1 + s * 64, &As[s][2048 + t * 8]);
  };
  auto load_b = [&](int s, int buf) {
#pragma unroll
    for (int kk = 0; kk < 2; ++kk)
#pragma unroll
      for (int nt = 0; nt < NTW; ++nt)
        bb[buf][kk][nt] = *(const bf16x8*)(wp + (size_t)nt * 16 * K + s * 64 + kk * 32);
  };

  // prologue FIFO order (per thread): A0(2) B0(LB) A1(2) B1(LB) [A2(2) A3(2)]
  stage_a(0);
  __builtin_amdgcn_sched_barrier(0);
  load_b(0, 0);
  __builtin_amdgcn_sched_barrier(0);
  stage_a(1);
  __builtin_amdgcn_sched_barrier(0);
  load_b(1, 1);
  __builtin_amdgcn_sched_barrier(0);
  if constexpr (NS == 4) {
    stage_a(2);
    stage_a(3);
    __builtin_amdgcn_sched_barrier(0);
  }

  const int sw = (l16 & 7) << 3;              // u16-unit read swizzle
#pragma unroll
  for (int ks = 0; ks < NS; ++ks) {
    // wait for A(ks)+B(ks) per exact FIFO position; later A/B stay in flight
    if (ks == 0)      vwait<(NS == 4 ? 6 + LB : 2 + LB)>();
    else if (ks == 1) { if constexpr (NS == 4) vwait<4 + LB>(); else vwait<0>(); }
    else if (ks == 2) vwait<LB>();
    else              vwait<0>();
    __builtin_amdgcn_s_barrier();             // all waves' A(ks) portions arrived
    __builtin_amdgcn_sched_barrier(0);
    const u16* Ab = As[ks];
#pragma unroll
    for (int kk = 0; kk < 2; ++kk) {
      bf16x8 a[4];
#pragma unroll
      for (int mt = 0; mt < 4; ++mt)
        a[mt] = *(const bf16x8*)(Ab + (mt * 16 + l16) * 64 + ((kk * 32 + quad * 8) ^ sw));
#pragma unroll
      for (int mt = 0; mt < 4; ++mt)
#pragma unroll
        for (int nt = 0; nt < NTW; ++nt)
          acc[mt][nt] = __builtin_amdgcn_mfma_f32_16x16x32_bf16(a[mt], bb[ks & 1][kk][nt], acc[mt][nt], 0, 0, 0);
    }
    if (ks + 2 < NS) load_b(ks + 2, ks & 1);  // WAR on bb[ks&1] after its MFMAs
    __builtin_amdgcn_sched_barrier(0);
  }

#pragma unroll
  for (int mt = 0; mt < 4; ++mt)
#pragma unroll
    for (int nt = 0; nt < NTW; ++nt) {
      int col = nbase + nt * 16 + l16;
      float bv = bias ? bias[col] : 0.f;
#pragma unroll
      for (int r = 0; r < 4; ++r) {
        int row = mbase + mt * 16 + quad * 4 + r;
        if (row < M) {
          float v = acc[mt][nt][r] + bv;
          if (out32) out32[(size_t)row * N + col] = v;
          else       out16[(size_t)row * N + col] = f2bf(v);
        }
      }
    }
  // fused el/er (all shfls wave-uniform; only stores guarded)
  if (al4 != nullptr) {
    float alv[NTW], arv[NTW];
#pragma unroll
    for (int nt = 0; nt < NTW; ++nt) {
      alv[nt] = al4[wave * 64 + nt * 16 + l16];
      arv[nt] = ar4 ? ar4[wave * 64 + nt * 16 + l16] : 0.f;
    }
#pragma unroll
    for (int mt = 0; mt < 4; ++mt) {
#pragma unroll
      for (int r = 0; r < 4; ++r) {
        float p = 0.f, q = 0.f;
#pragma unroll
        for (int nt = 0; nt < NTW; ++nt) {
          p += acc[mt][nt][r] * alv[nt];
          q += acc[mt][nt][r] * arv[nt];
        }
#pragma unroll
        for (int off = 1; off < 16; off <<= 1) {
          p += __shfl_xor(p, off);
          q += __shfl_xor(q, off);
        }
        int row = mbase + mt * 16 + quad * 4 + r;
        if (l16 == 0 && row < M) {
          el[row * 4 + wave] = p;
          if (ar4) er[row * 4 + wave] = q;
        }
      }
    }
  }
}

// ---- er[n][h] = sum_k X[n][k](bf16) * wr[k][h]; paper + author in one launch ----
__global__ __launch_bounds__(256) void er_wr2(
    const u16* __restrict__ Xp, const u16* __restrict__ Xa,
    const float* __restrict__ wrp, const float* __restrict__ wra,
    float* __restrict__ erp, float* __restrict__ era, int Np, int Na, int K)
{
  int nblkP = (Np + 3) / 4;
  int bid = blockIdx.x;
  const u16* X; const float* wr; float* er; int nid, Nn;
  if (bid < nblkP) { X = Xp; wr = wrp; er = erp; Nn = Np; nid = bid * 4 + (threadIdx.x >> 6); }
  else { X = Xa; wr = wra; er = era; Nn = Na; nid = (bid - nblkP) * 4 + (threadIdx.x >> 6); }
  if (nid >= Nn) return;
  int lane = threadIdx.x & 63;
  float a0 = 0.f, a1 = 0.f, a2 = 0.f, a3 = 0.f;
  for (int k = lane; k < K; k += 64) {
    float xv = bf2f(X[(size_t)nid * K + k]);
    const float* w = wr + k * 4;
    a0 += xv * w[0]; a1 += xv * w[1]; a2 += xv * w[2]; a3 += xv * w[3];
  }
  for (int off = 1; off < 64; off <<= 1) {
    a0 += __shfl_xor(a0, off); a1 += __shfl_xor(a1, off);
    a2 += __shfl_xor(a2, off); a3 += __shfl_xor(a3, off);
  }
  if (lane == 0) {
    er[nid * 4 + 0] = a0; er[nid * 4 + 1] = a1;
    er[nid * 4 + 2] = a2; er[nid * 4 + 3] = a3;
  }
}

// ================== bucketed CSR build ==================
// buckets of 1024 dsts; layout: rel0 (cites, Np): buckets [0,NBC),
// rel1 (writes, Np): [NBC,2*NBC), rel2 (written, Na): [2*NBC, 2*NBC+NBA).
// packed staging word: src (18 bits) | dstLow10 << 18.

__global__ __launch_bounds__(256) void zero3(int* p, int n) {
  int i = blockIdx.x * 256 + threadIdx.x;
  if (i < n) p[i] = 0;
}

// per-block LDS bucket histogram -> few global atomics
__global__ __launch_bounds__(256) void p1hist(
    const int* __restrict__ dC, const int* __restrict__ dW, const int* __restrict__ dR,
    int E, int NBC, int* __restrict__ bcnt)
{
  int nbE = (E + 4095) >> 12;
  int bi = blockIdx.x, rel = bi / nbE, ch = bi - rel * nbE;
  const int* d = rel == 0 ? dC : (rel == 1 ? dW : dR);
  int rbase = rel * NBC;
  int e0 = ch << 12, e1 = min(E, e0 + 4096);
  __shared__ int cnt[128];
  int t = threadIdx.x;
  if (t < 128) cnt[t] = 0;
  __syncthreads();
  for (int e = e0 + t; e < e1; e += 256) atomicAdd(&cnt[d[e] >> 10], 1);
  __syncthreads();
  if (t < 128) { int n = cnt[t]; if (n) atomicAdd(&bcnt[rbase + t], n); }
}

// exclusive scan of bucket counts -> bases + cursors (nb <= 1024)
__global__ __launch_bounds__(1024) void bscan(
    const int* __restrict__ bcnt, int* __restrict__ bbase, int* __restrict__ gcur, int nb)
{
  __shared__ int sm[1024];
  int t = threadIdx.x;
  int v = (t < nb) ? bcnt[t] : 0;
  sm[t] = v; __syncthreads();
  for (int off = 1; off < 1024; off <<= 1) {
    int add = (t >= off) ? sm[t - off] : 0;
    __syncthreads();
    sm[t] += add;
    __syncthreads();
  }
  if (t < nb) { int e = sm[t] - v; bbase[t] = e; gcur[t] = e; }
}

// scatter edges into bucket-contiguous staging; one global atomic per (block,bucket);
// each (block,bucket) run is contiguous -> L2-merged writes
__global__ __launch_bounds__(256) void p1scat(
    const int* __restrict__ sC, const int* __restrict__ dC,
    const int* __restrict__ sW, const int* __restrict__ dW,
    const int* __restrict__ sR, const int* __restrict__ dR,
    int E, int NBC, int* __restrict__ gcur, u32* __restrict__ stage3)
{
  int nbE = (E + 4095) >> 12;
  int bi = blockIdx.x, rel = bi / nbE, ch = bi - rel * nbE;
  const int *s, *d;
  if (rel == 0) { s = sC; d = dC; }
  else if (rel == 1) { s = sW; d = dW; }
  else { s = sR; d = dR; }
  int rbase = rel * NBC;
  int e0 = ch << 12, e1 = min(E, e0 + 4096);
  __shared__ int cnt[128], cur[128], gpos[128];
  int t = threadIdx.x;
  if (t < 128) { cnt[t] = 0; cur[t] = 0; }
  __syncthreads();
  for (int e = e0 + t; e < e1; e += 256) atomicAdd(&cnt[d[e] >> 10], 1);
  __syncthreads();
  if (t < 128) { int n = cnt[t]; gpos[t] = n ? atomicAdd(&gcur[rbase + t], n) : 0; }
  __syncthreads();
  for (int e = e0 + t; e < e1; e += 256) {
    int dd = d[e], b = dd >> 10;
    int slot = atomicAdd(&cur[b], 1);
    stage3[gpos[b] + slot] = (u32)(s[e] & 0x3FFFF) | ((u32)(dd & 1023) << 18);
  }
}

// per-bucket fine counting sort: produces rp + srcs (replaces scans + fill)
__global__ __launch_bounds__(256) void p2fine(
    const u32* __restrict__ stage3, const int* __restrict__ bcnt, const int* __restrict__ bbase,
    int* __restrict__ rpC, int* __restrict__ rpW, int* __restrict__ rpR,
    int* __restrict__ srcsC, int* __restrict__ srcsW, int* __restrict__ srcsR,
    int E, int Np, int Na, int NBC)
{
  int bid = blockIdx.x, t = threadIdx.x;
  int rel, b, Nrel; int* rp; int* srcs;
  if (bid < NBC)          { rel = 0; b = bid;            Nrel = Np; rp = rpC; srcs = srcsC; }
  else if (bid < 2 * NBC) { rel = 1; b = bid - NBC;      Nrel = Np; rp = rpW; srcs = srcsW; }
  else                    { rel = 2; b = bid - 2 * NBC;  Nrel = Na; rp = rpR; srcs = srcsR; }
  int base = bbase[bid], cnt = bcnt[bid];
  int csrbase = base - rel * E;
  int dstbase = b << 10;
  int ndst = Nrel - dstbase; if (ndst > 1024) ndst = 1024;
  __shared__ int h[1024], cur[1024], tmp[256];
  for (int i = t; i < 1024; i += 256) h[i] = 0;
  __syncthreads();
  for (int i = t; i < cnt; i += 256) atomicAdd(&h[stage3[base + i] >> 18], 1);
  __syncthreads();
  // exclusive scan over 1024 via 4-per-thread + 256-scan
  int s4 = h[4 * t] + h[4 * t + 1] + h[4 * t + 2] + h[4 * t + 3];
  tmp[t] = s4; __syncthreads();
  for (int off = 1; off < 256; off <<= 1) {
    int add = (t >= off) ? tmp[t - off] : 0;
    __syncthreads();
    tmp[t] += add;
    __syncthreads();
  }
  int run = tmp[t] - s4;
#pragma unroll
  for (int j = 0; j < 4; ++j) { int hv = h[4 * t + j]; cur[4 * t + j] = run; run += hv; }
  __syncthreads();
  for (int d = t; d < ndst; d += 256) rp[dstbase + d] = csrbase + cur[d];
  if (bid == 0 && t == 0) { rpC[Np] = E; rpW[Np] = E; rpR[Na] = E; }
  __syncthreads();
  for (int i = t; i < cnt; i += 256) {
    u32 w = stage3[base + i];
    int lp = atomicAdd(&cur[w >> 18], 1);
    srcs[csrbase + lp] = (int)(w & 0x3FFFF);
  }
}

// ---- softmax-agg helpers; packed f32 accumulate ----
static __device__ __forceinline__ void pk2(float2& a, unsigned int u, float w) {
  union { unsigned int i; float f; } lo, hi;
  lo.i = u << 16; hi.i = u & 0xffff0000u;
  a.x += w * lo.f;
  a.y += w * hi.f;
}
static __device__ __forceinline__ void edge1(
    int sid, int sl, int hh, const float* __restrict__ el, float ern,
    const u16* __restrict__ fs, float2* acc2, float& sw)
{
  float v = el[(size_t)sid * 4 + hh] + ern;
  uint4 r = *(const uint4*)(fs + (size_t)sid * 256 + sl * 8);
  v = v > 0.f ? v : 0.2f * v;
  float w = __expf(v);
  sw += w;
  pk2(acc2[0], r.x, w); pk2(acc2[1], r.y, w);
  pk2(acc2[2], r.z, w); pk2(acc2[3], r.w, w);
}
static __device__ __forceinline__ void edge4(
    int sid0, int sid1, int sid2, int sid3, int sl, int hh,
    const float* __restrict__ el, float ern, const u16* __restrict__ fs,
    float2* acc2, float& sw)
{
  float v0 = el[(size_t)sid0 * 4 + hh] + ern;
  float v1 = el[(size_t)sid1 * 4 + hh] + ern;
  float v2 = el[(size_t)sid2 * 4 + hh] + ern;
  float v3 = el[(size_t)sid3 * 4 + hh] + ern;
  uint4 r0 = *(const uint4*)(fs + (size_t)sid0 * 256 + sl * 8);
  uint4 r1 = *(const uint4*)(fs + (size_t)sid1 * 256 + sl * 8);
  uint4 r2 = *(const uint4*)(fs + (size_t)sid2 * 256 + sl * 8);
  uint4 r3 = *(const uint4*)(fs + (size_t)sid3 * 256 + sl * 8);
  v0 = v0 > 0.f ? v0 : 0.2f * v0;
  v1 = v1 > 0.f ? v1 : 0.2f * v1;
  v2 = v2 > 0.f ? v2 : 0.2f * v2;
  v3 = v3 > 0.f ? v3 : 0.2f * v3;
  float w0 = __expf(v0), w1 = __expf(v1), w2 = __expf(v2), w3 = __expf(v3);
  sw += (w0 + w1) + (w2 + w3);
  pk2(acc2[0], r0.x, w0); pk2(acc2[1], r0.y, w0);
  pk2(acc2[2], r0.z, w0); pk2(acc2[3], r0.w, w0);
  pk2(acc2[0], r1.x, w1); pk2(acc2[1], r1.y, w1);
  pk2(acc2[2], r1.z, w1); pk2(acc2[3], r1.w, w1);
  pk2(acc2[0], r2.x, w2); pk2(acc2[1], r2.y, w2);
  pk2(acc2[2], r2.z, w2); pk2(acc2[3], r2.w, w2);
  pk2(acc2[0], r3.x, w3); pk2(acc2[1], r3.y, w3);
  pk2(acc2[2], r3.z, w3); pk2(acc2[3], r3.w, w3);
}

// ---- paper-dst: wave per dst; half-wave 0 = rel cites, half-wave 1 = rel writes
// (both relations' load chains in flight concurrently); 4-deep edge unroll ----
__global__ __launch_bounds__(256) void agg_paper(
    const int* __restrict__ rp0, const int* __restrict__ srcs0,
    const float* __restrict__ el0, const float* __restrict__ er0,
    const u16* __restrict__ fs0,
    const int* __restrict__ rp1, const int* __restrict__ srcs1,
    const float* __restrict__ el1, const float* __restrict__ er1,
    const u16* __restrict__ fs1,
    const float* __restrict__ bias0, const float* __restrict__ bias1,
    u16* __restrict__ out, int Nd, int relu)
{
  int nid = blockIdx.x * 4 + (threadIdx.x >> 6);
  if (nid >= Nd) return;
  int lane = threadIdx.x & 63;
  int half = lane >> 5, sl = lane & 31, hh = sl >> 3;
  const int* rp     = half ? rp1 : rp0;
  const int* srcs   = half ? srcs1 : srcs0;
  const float* el   = half ? el1 : el0;
  const float* er   = half ? er1 : er0;
  const u16* fs     = half ? fs1 : fs0;
  float ern = er[(size_t)nid * 4 + hh];
  int s0 = rp[nid], s1 = rp[nid + 1];
  float2 acc2[4] = {{0.f,0.f},{0.f,0.f},{0.f,0.f},{0.f,0.f}};
  float sw = 0.f;
  int i = s0;
  for (; i + 3 < s1; i += 4)
    edge4(srcs[i], srcs[i + 1], srcs[i + 2], srcs[i + 3], sl, hh, el, ern, fs, acc2, sw);
  for (; i < s1; ++i)
    edge1(srcs[i], sl, hh, el, ern, fs, acc2, sw);
  // per-relation (per-half) normalize, then sum the two relations across halves
  float inv = sw > 0.f ? 1.f / sw : 0.f;
  float o[8];
#pragma unroll
  for (int k = 0; k < 4; ++k) {
    o[2 * k]     = acc2[k].x * inv;
    o[2 * k + 1] = acc2[k].y * inv;
  }
#pragma unroll
  for (int j = 0; j < 8; ++j) o[j] += __shfl_xor(o[j], 32);
  if (half == 0) {
    const float* bp0 = bias0 + sl * 8;
    const float* bp1 = bias1 + sl * 8;
    bf16x8 r;
#pragma unroll
    for (int j = 0; j < 8; ++j) {
      float v = o[j] + bp0[j] + bp1[j];
      if (relu) v = fmaxf(v, 0.f);
      r[j] = (short)f2bf(v);
    }
    *(bf16x8*)(out + (size_t)nid * 256 + sl * 8) = r;
  }
}

// ---- author-dst: rel written; half-waves split edges, 4-deep unroll ----
__global__ __launch_bounds__(256) void agg_author(
    const int* __restrict__ rp0, const int* __restrict__ srcs0,
    const float* __restrict__ el0, const float* __restrict__ er0,
    const u16* __restrict__ fs0,
    const float* __restrict__ bias0, u16* __restrict__ out, int Nd, int relu)
{
  int nid = blockIdx.x * 4 + (threadIdx.x >> 6);
  if (nid >= Nd) return;
  int lane = threadIdx.x & 63;
  int half = lane >> 5, sl = lane & 31, hh = sl >> 3;
  float ern = er0[(size_t)nid * 4 + hh];
  int s0 = rp0[nid], s1 = rp0[nid + 1];
  float2 acc2[4] = {{0.f,0.f},{0.f,0.f},{0.f,0.f},{0.f,0.f}};
  float sw = 0.f;
  int i = s0 + half;
  for (; i + 6 < s1; i += 8)
    edge4(srcs0[i], srcs0[i + 2], srcs0[i + 4], srcs0[i + 6], sl, hh, el0, ern, fs0, acc2, sw);
  for (; i < s1; i += 2)
    edge1(srcs0[i], sl, hh, el0, ern, fs0, acc2, sw);
  sw += __shfl_xor(sw, 32);
  float inv = sw > 0.f ? 1.f / sw : 0.f;
  float o[8];
#pragma unroll
  for (int k = 0; k < 4; ++k) {
    o[2 * k]     = (acc2[k].x + __shfl_xor(acc2[k].x, 32)) * inv;
    o[2 * k + 1] = (acc2[k].y + __shfl_xor(acc2[k].y, 32)) * inv;
  }
  if (half == 0) {
    const float* bp0 = bias0 + sl * 8;
    bf16x8 r;
#pragma unroll
    for (int j = 0; j < 8; ++j) {
      float v = o[j] + bp0[j];
      if (relu) v = fmaxf(v, 0.f);
      r[j] = (short)f2bf(v);
    }
    *(bf16x8*)(out + (size_t)nid * 256 + sl * 8) = r;
  }
}

static inline int cdiv(int a, int b) { return (a + b - 1) / b; }

extern "C" void kernel_launch(void* const* d_in, const int* in_sizes, int n_in,
                              void* d_out, int out_size, void* d_ws, size_t ws_size,
                              hipStream_t stream)
{
  const float* xp   = (const float*)d_in[0];
  const float* xa   = (const float*)d_in[1];
  const float* W0   = (const float*)d_in[2];   // [3][128][256]
  const float* al0  = (const float*)d_in[3];   // [3][4][64]
  const float* ar0  = (const float*)d_in[4];
  const float* b0   = (const float*)d_in[5];   // [3][256]
  const float* W1   = (const float*)d_in[6];   // [3][256][256]
  const float* al1  = (const float*)d_in[7];
  const float* ar1  = (const float*)d_in[8];
  const float* b1   = (const float*)d_in[9];
  const float* linw = (const float*)d_in[10];  // [256][192]
  const float* linb = (const float*)d_in[11];  // [192]
  const int* srcC = (const int*)d_in[12];
  const int* dstC = (const int*)d_in[13];
  const int* srcW = (const int*)d_in[14];
  const int* dstW = (const int*)d_in[15];
  const int* srcR = (const int*)d_in[16];
  const int* dstR = (const int*)d_in[17];
  float* out = (float*)d_out;

  const int Np = in_sizes[0] / 128;
  const int Na = in_sizes[1] / 128;
  const int E  = in_sizes[12];

  char* base = (char*)d_ws;
  size_t off = 0;
  auto alloc = [&](size_t bytes) -> void* {
    void* r = base + off;
    off += (bytes + 255) & ~(size_t)255;
    return r;
  };
  u16* Wt0  = (u16*)alloc((size_t)3 * 256 * 128 * 2);   // [r][n=256][k=128] bf16
  u16* Wt1  = (u16*)alloc((size_t)3 * 256 * 256 * 2);   // [r][n=256][k=256] bf16
  u16* Wtl  = (u16*)alloc((size_t)192 * 256 * 2);       // [n=192][k=256] bf16
  float* wr01 = (float*)alloc(128 * 4 * 4);
  float* wr02 = (float*)alloc(128 * 4 * 4);
  float* wr11 = (float*)alloc(256 * 4 * 4);
  float* wr12 = (float*)alloc(256 * 4 * 4);
  u16* xpb  = (u16*)alloc((size_t)Np * 128 * 2);
  u16* xab  = (u16*)alloc((size_t)Na * 128 * 2);
  u16* fs0p = (u16*)alloc((size_t)Np * 256 * 2);
  u16* fs1a = (u16*)alloc((size_t)Na * 256 * 2);
  u16* fs2p = (u16*)alloc((size_t)Np * 256 * 2);
  u16* h1p  = (u16*)alloc((size_t)Np * 256 * 2);
  u16* h1a  = (u16*)alloc((size_t)Na * 256 * 2);
  float* el0 = (float*)alloc((size_t)Np * 4 * 4);
  float* er0 = (float*)alloc((size_t)Np * 4 * 4);
  float* el1 = (float*)alloc((size_t)Na * 4 * 4);
  float* er1 = (float*)alloc((size_t)Np * 4 * 4);
  float* el2 = (float*)alloc((size_t)Np * 4 * 4);
  float* er2 = (float*)alloc((size_t)Na * 4 * 4);
  int* rpC  = (int*)alloc((size_t)(Np + 1) * 4);
  int* rpW  = (int*)alloc((size_t)(Np + 1) * 4);
  int* rpR  = (int*)alloc((size_t)(Na + 1) * 4);
  int* srcsC = (int*)alloc((size_t)E * 4);
  int* srcsW = (int*)alloc((size_t)E * 4);
  int* srcsR = (int*)alloc((size_t)E * 4);
  int* bcnt  = (int*)alloc(1024 * 4);
  int* bbase = (int*)alloc(1024 * 4);
  int* gcur  = (int*)alloc(1024 * 4);
  // staging for bucketed sort aliases fs0p (dead until first gemm, 6MB << 51MB)
  u32* stage3 = (u32*)fs0p;

  // ---- input conversion + weight prep ----
  cvt2<<<cdiv(Np * 32 + Na * 32, 256), 256, 0, stream>>>(xp, xa, xpb, xab, Np * 32, Na * 32);
  transpose3<<<cdiv(3 * 128 * 256, 256), 256, 0, stream>>>(W0, Wt0, 3, 128, 256);
  transpose3<<<cdiv(3 * 256 * 256, 256), 256, 0, stream>>>(W1, Wt1, 3, 256, 256);
  transpose3<<<cdiv(256 * 192, 256), 256, 0, stream>>>(linw, Wtl, 1, 256, 192);
  build_wr2<<<cdiv(2 * 128 * 4, 256), 256, 0, stream>>>(W0 + 32768, W0 + 65536,
                                                        ar0 + 256, ar0 + 512, wr01, wr02, 128);
  build_wr2<<<cdiv(2 * 256 * 4, 256), 256, 0, stream>>>(W1 + 65536, W1 + 131072,
                                                        ar1 + 256, ar1 + 512, wr11, wr12, 256);

  // ---- bucketed CSR build ----
  const int NBC = cdiv(Np, 1024);            // paper buckets (per relation)
  const int NBA = cdiv(Na, 1024);            // author buckets
  const int NBtot = 2 * NBC + NBA;
  const int nbE = cdiv(E, 4096);
  zero3<<<cdiv(NBtot, 256), 256, 0, stream>>>(bcnt, NBtot);
  p1hist<<<3 * nbE, 256, 0, stream>>>(dstC, dstW, dstR, E, NBC, bcnt);
  bscan<<<1, 1024, 0, stream>>>(bcnt, bbase, gcur, NBtot);
  p1scat<<<3 * nbE, 256, 0, stream>>>(srcC, dstC, srcW, dstW, srcR, dstR,
                                      E, NBC, gcur, stage3);
  p2fine<<<NBtot, 256, 0, stream>>>(stage3, bcnt, bbase, rpC, rpW, rpR,
                                    srcsC, srcsW, srcsR, E, Np, Na, NBC);

  auto layer = [&](const u16* inP, const u16* inA, const u16* WtL, int K,
                   const float* alL, const float* arL,
                   const float* wr1, const float* wr2, const float* bL,
                   u16* outP, u16* outA, int relu) {
    size_t wsz = (size_t)256 * K;
    if (K == 128) {
      gemm_rb<128, 4><<<dim3(cdiv(Np, 64)), 256, 0, stream>>>(
          inP, WtL, fs0p, nullptr, nullptr, alL, arL, el0, er0, Np);
      gemm_rb<128, 4><<<dim3(cdiv(Na, 64)), 256, 0, stream>>>(
          inA, WtL + wsz, fs1a, nullptr, nullptr, alL + 256, nullptr, el1, nullptr, Na);
      gemm_rb<128, 4><<<dim3(cdiv(Np, 64)), 256, 0, stream>>>(
          inP, WtL + 2 * wsz, fs2p, nullptr, nullptr, alL + 512, nullptr, el2, nullptr, Np);
    } else {
      gemm_rb<256, 4><<<dim3(cdiv(Np, 64)), 256, 0, stream>>>(
          inP, WtL, fs0p, nullptr, nullptr, alL, arL, el0, er0, Np);
      gemm_rb<256, 4><<<dim3(cdiv(Na, 64)), 256, 0, stream>>>(
          inA, WtL + wsz, fs1a, nullptr, nullptr, alL + 256, nullptr, el1, nullptr, Na);
      gemm_rb<256, 4><<<dim3(cdiv(Np, 64)), 256, 0, stream>>>(
          inP, WtL + 2 * wsz, fs2p, nullptr, nullptr, alL + 512, nullptr, el2, nullptr, Np);
    }
    er_wr2<<<cdiv(Np, 4) + cdiv(Na, 4), 256, 0, stream>>>(inP, inA, wr1, wr2, er1, er2, Np, Na, K);
    agg_paper<<<cdiv(Np, 4), 256, 0, stream>>>(rpC, srcsC, el0, er0, fs0p,
                                               rpW, srcsW, el1, er1, fs1a,
                                               bL, bL + 256, outP, Np, relu);
    agg_author<<<cdiv(Na, 4), 256, 0, stream>>>(rpR, srcsR, el2, er2, fs2p,
                                                bL + 512, outA, Na, relu);
  };

  layer(xpb, xab, Wt0, 128, al0, ar0, wr01, wr02, b0, h1p, h1a, 1);
  layer(h1p, h1a, Wt1, 256, al1, ar1, wr11, wr12, b1, h1p, h1a, 0);

  // ---- final linear ----
  gemm_rb<256, 3><<<dim3(cdiv(Np, 64)), 256, 0, stream>>>(
      h1p, Wtl, nullptr, out, linb, nullptr, nullptr, nullptr, nullptr, Np);
}

// Round 6
// 793.146 us; speedup vs baseline: 1.1980x; 1.1980x over previous
//
#include <hip/hip_runtime.h>

typedef unsigned short u16;
typedef unsigned int u32;
typedef __attribute__((ext_vector_type(8))) short bf16x8;
typedef __attribute__((ext_vector_type(4))) float f32x4;

static __device__ __forceinline__ float bf2f(u16 u) {
  union { unsigned int i; float f; } v; v.i = ((unsigned int)u) << 16; return v.f;
}
static __device__ __forceinline__ u16 f2bf(float f) {
  union { float f; unsigned int i; } v; v.f = f;
  unsigned int i = v.i;
  return (u16)((i + 0x7FFFu + ((i >> 16) & 1u)) >> 16);
}

// async global->LDS, 16B per lane (guide §5: width=16 is the fast path)
static __device__ __forceinline__ void gl16(const u16* g, u16* l) {
  __builtin_amdgcn_global_load_lds(
      (const __attribute__((address_space(1))) unsigned int*)g,
      (__attribute__((address_space(3))) unsigned int*)l, 16, 0, 0);
}

// ---- convert f32 -> bf16 for both inputs in one launch ----
__global__ __launch_bounds__(256) void cvt2(const float* __restrict__ a, const float* __restrict__ b,
                                            u16* __restrict__ da, u16* __restrict__ db,
                                            int n4a, int n4b)
{
  int i = blockIdx.x * 256 + threadIdx.x;
  const float* s; u16* d; int j;
  if (i < n4a) { s = a; d = da; j = i; }
  else { j = i - n4a; if (j >= n4b) return; s = b; d = db; }
  float4 v = ((const float4*)s)[j];
  ushort4 r;
  r.x = f2bf(v.x); r.y = f2bf(v.y); r.z = f2bf(v.z); r.w = f2bf(v.w);
  ((ushort4*)d)[j] = r;
}

// ---- transpose R chunks: dst[r][n*K+k] (bf16) = src[r][k*N+n] (f32) ----
__global__ __launch_bounds__(256) void transpose3(const float* __restrict__ src,
                                                  u16* __restrict__ dst, int R, int K, int N)
{
  int idx = blockIdx.x * 256 + threadIdx.x;
  if (idx >= R * K * N) return;
  int r = idx / (K * N), rem = idx - r * K * N;
  int k = rem / N, n = rem - k * N;
  dst[(size_t)r * N * K + (size_t)n * K + k] = f2bf(src[idx]);
}

// ---- wr for two relations of one layer in one launch ----
__global__ __launch_bounds__(256) void build_wr2(
    const float* __restrict__ Wa, const float* __restrict__ Wb,
    const float* __restrict__ ara, const float* __restrict__ arb,
    float* __restrict__ wra, float* __restrict__ wrb, int K)
{
  int idx = blockIdx.x * 256 + threadIdx.x;
  if (idx >= 2 * K * 4) return;
  int sel = idx / (K * 4), rem = idx - sel * K * 4;
  int k = rem >> 2, h = rem & 3;
  const float* W = sel ? Wb : Wa;
  const float* ar = sel ? arb : ara;
  float s = 0.f;
  for (int d = 0; d < 64; ++d)
    s += W[(size_t)k * 256 + h * 64 + d] * ar[h * 64 + d];
  (sel ? wrb : wra)[rem] = s;
}

// ======== round-4 GEMM core as a macro-like inline: LDS-staged, double-buffered,
// counted vmcnt, fused el/er epilogue. Used by gemm_rb (final linear) and gemm3. ========
template<int K, int NTW>
static __device__ __forceinline__ void gemm_core(
    const u16* __restrict__ X, const u16* __restrict__ Wt,
    u16* __restrict__ out16, float* __restrict__ out32,
    const float* __restrict__ bias,
    const float* __restrict__ al4, const float* __restrict__ ar4,
    float* __restrict__ el, float* __restrict__ er, int M, int mblk,
    u16 (*As)[64 * 64])
{
  constexpr int NS = K / 64;                 // 64-wide K stages
  const int N = NTW * 16 * 4;
  const int t = threadIdx.x;
  const int wave = t >> 6, lane = t & 63;
  const int quad = lane >> 4, l16 = lane & 15;
  const int mbase = mblk * 64;
  const int nbase = wave * (NTW * 16);

  // staging: thread t covers rows r0 (round 0) and r1 (round 1), 16B each.
  // physical chunk = t&7; source chunk = (t&7) ^ (row&7)  (XOR involution)
  int r0 = t >> 3, r1 = 32 + (t >> 3);
  int c0 = (t & 7) ^ (r0 & 7);
  int c1 = (t & 7) ^ (r1 & 7);
  int rr0 = mbase + r0; if (rr0 >= M) rr0 = M - 1;   // clamp tail (stores guarded)
  int rr1 = mbase + r1; if (rr1 >= M) rr1 = M - 1;
  const u16* g0 = X + (size_t)rr0 * K + c0 * 8;
  const u16* g1 = X + (size_t)rr1 * K + c1 * 8;

  const u16* wp = Wt + (size_t)(nbase + l16) * K + quad * 8;

  f32x4 acc[4][NTW];
#pragma unroll
  for (int mt = 0; mt < 4; ++mt)
#pragma unroll
    for (int nt = 0; nt < NTW; ++nt) acc[mt][nt] = (f32x4){0.f, 0.f, 0.f, 0.f};

  bf16x8 bb[2][NTW];                          // one stage of B, prefetched

  auto stage_a = [&](int s, int b) {
    gl16(g0 + s * 64, &As[b][t * 8]);
    gl16(g1 + s * 64, &As[b][2048 + t * 8]);
  };
  auto load_b = [&](int s) {
#pragma unroll
    for (int kk = 0; kk < 2; ++kk)
#pragma unroll
      for (int nt = 0; nt < NTW; ++nt)
        bb[kk][nt] = *(const bf16x8*)(wp + (size_t)nt * 16 * K + s * 64 + kk * 32);
  };

  // prologue: A0 (2 vmem) | B0 (2*NTW vmem) | A1 (2 vmem) — order pinned
  stage_a(0, 0);
  __builtin_amdgcn_sched_barrier(0);
  load_b(0);
  __builtin_amdgcn_sched_barrier(0);
  if (NS > 1) stage_a(1, 1);
  __builtin_amdgcn_sched_barrier(0);

  const int sw = (l16 & 7) << 3;              // u16-unit read swizzle
#pragma unroll
  for (int ks = 0; ks < NS; ++ks) {
    // steady state: leave only next A-stage (2 ops) in flight; A(ks)+B(ks) done
    if (ks + 1 < NS) asm volatile("s_waitcnt vmcnt(2)" ::: "memory");
    else             asm volatile("s_waitcnt vmcnt(0)" ::: "memory");
    __builtin_amdgcn_s_barrier();
    __builtin_amdgcn_sched_barrier(0);
    const u16* Ab = As[ks & 1];
#pragma unroll
    for (int kk = 0; kk < 2; ++kk) {
      bf16x8 a[4];
#pragma unroll
      for (int mt = 0; mt < 4; ++mt)
        a[mt] = *(const bf16x8*)(Ab + (mt * 16 + l16) * 64 + ((kk * 32 + quad * 8) ^ sw));
#pragma unroll
      for (int mt = 0; mt < 4; ++mt)
#pragma unroll
        for (int nt = 0; nt < NTW; ++nt)
          acc[mt][nt] = __builtin_amdgcn_mfma_f32_16x16x32_bf16(a[mt], bb[kk][nt], acc[mt][nt], 0, 0, 0);
    }
    if (ks + 1 < NS) load_b(ks + 1);          // B prefetch (WAR after compute)
    __builtin_amdgcn_sched_barrier(0);
    __builtin_amdgcn_s_barrier();             // all waves done reading As[ks&1]
    __builtin_amdgcn_sched_barrier(0);
    if (ks + 2 < NS) {
      stage_a(ks + 2, ks & 1);                // overwrite just-consumed buffer
      __builtin_amdgcn_sched_barrier(0);
    }
  }

#pragma unroll
  for (int mt = 0; mt < 4; ++mt)
#pragma unroll
    for (int nt = 0; nt < NTW; ++nt) {
      int col = nbase + nt * 16 + l16;
      float bv = bias ? bias[col] : 0.f;
#pragma unroll
      for (int r = 0; r < 4; ++r) {
        int row = mbase + mt * 16 + quad * 4 + r;
        if (row < M) {
          float v = acc[mt][nt][r] + bv;
          if (out32) out32[(size_t)row * N + col] = v;
          else       out16[(size_t)row * N + col] = f2bf(v);
        }
      }
    }
  // fused el/er (all shfls wave-uniform; only stores guarded)
  if (al4 != nullptr) {
    float alv[NTW], arv[NTW];
#pragma unroll
    for (int nt = 0; nt < NTW; ++nt) {
      alv[nt] = al4[wave * 64 + nt * 16 + l16];
      arv[nt] = ar4 ? ar4[wave * 64 + nt * 16 + l16] : 0.f;
    }
#pragma unroll
    for (int mt = 0; mt < 4; ++mt) {
#pragma unroll
      for (int r = 0; r < 4; ++r) {
        float p = 0.f, q = 0.f;
#pragma unroll
        for (int nt = 0; nt < NTW; ++nt) {
          p += acc[mt][nt][r] * alv[nt];
          q += acc[mt][nt][r] * arv[nt];
        }
#pragma unroll
        for (int off = 1; off < 16; off <<= 1) {
          p += __shfl_xor(p, off);
          q += __shfl_xor(q, off);
        }
        int row = mbase + mt * 16 + quad * 4 + r;
        if (l16 == 0 && row < M) {
          el[row * 4 + wave] = p;
          if (ar4) er[row * 4 + wave] = q;
        }
      }
    }
  }
}

// ---- standalone GEMM (final linear) ----
template<int K, int NTW>
__global__ __launch_bounds__(256, 3) void gemm_rb(
    const u16* __restrict__ X, const u16* __restrict__ Wt,
    u16* __restrict__ out16, float* __restrict__ out32,
    const float* __restrict__ bias,
    const float* __restrict__ al4, const float* __restrict__ ar4,
    float* __restrict__ el, float* __restrict__ er, int M)
{
  __shared__ __align__(16) u16 As[2][64 * 64];   // 2 x 8KB
  gemm_core<K, NTW>(X, Wt, out16, out32, bias, al4, ar4, el, er, M, blockIdx.x, As);
}

// ---- fused 3-relation layer GEMM: one launch covers rel0 (paper), rel1 (author),
// rel2 (paper). Block id decodes relation; per-relation pointers selected uniformly.
// Same core as gemm_rb -> bit-identical results, 1 launch instead of 3, author
// blocks fill paper-tail CUs. ----
template<int K>
__global__ __launch_bounds__(256, 3) void gemm3(
    const u16* __restrict__ Xp, const u16* __restrict__ Xa,
    const u16* __restrict__ Wt,          // [3][256][K]
    u16* __restrict__ fs0, u16* __restrict__ fs1, u16* __restrict__ fs2,
    const float* __restrict__ al,        // [3][256]
    const float* __restrict__ ar0v,      // [256], rel0 only
    float* __restrict__ el0, float* __restrict__ el1, float* __restrict__ el2,
    float* __restrict__ er0,
    int Np, int Na, int nblkP, int nblkA)
{
  __shared__ __align__(16) u16 As[2][64 * 64];
  int bid = blockIdx.x;
  int rel, lb;
  if (bid < nblkP)              { rel = 0; lb = bid; }
  else if (bid < nblkP + nblkA) { rel = 1; lb = bid - nblkP; }
  else                          { rel = 2; lb = bid - nblkP - nblkA; }
  const u16* X  = (rel == 1) ? Xa : Xp;
  const int  M  = (rel == 1) ? Na : Np;
  const u16* W  = Wt + (size_t)rel * 256 * K;
  u16* out      = rel == 0 ? fs0 : (rel == 1 ? fs1 : fs2);
  const float* al4 = al + rel * 256;
  const float* ar4 = (rel == 0) ? ar0v : nullptr;
  float* el     = rel == 0 ? el0 : (rel == 1 ? el1 : el2);
  float* er     = (rel == 0) ? er0 : nullptr;
  gemm_core<K, 4>(X, W, out, nullptr, nullptr, al4, ar4, el, er, M, lb, As);
}

// ---- er[n][h] = sum_k X[n][k](bf16) * wr[k][h]; paper + author in one launch ----
__global__ __launch_bounds__(256) void er_wr2(
    const u16* __restrict__ Xp, const u16* __restrict__ Xa,
    const float* __restrict__ wrp, const float* __restrict__ wra,
    float* __restrict__ erp, float* __restrict__ era, int Np, int Na, int K)
{
  int nblkP = (Np + 3) / 4;
  int bid = blockIdx.x;
  const u16* X; const float* wr; float* er; int nid, Nn;
  if (bid < nblkP) { X = Xp; wr = wrp; er = erp; Nn = Np; nid = bid * 4 + (threadIdx.x >> 6); }
  else { X = Xa; wr = wra; er = era; Nn = Na; nid = (bid - nblkP) * 4 + (threadIdx.x >> 6); }
  if (nid >= Nn) return;
  int lane = threadIdx.x & 63;
  float a0 = 0.f, a1 = 0.f, a2 = 0.f, a3 = 0.f;
  for (int k = lane; k < K; k += 64) {
    float xv = bf2f(X[(size_t)nid * K + k]);
    const float* w = wr + k * 4;
    a0 += xv * w[0]; a1 += xv * w[1]; a2 += xv * w[2]; a3 += xv * w[3];
  }
  for (int off = 1; off < 64; off <<= 1) {
    a0 += __shfl_xor(a0, off); a1 += __shfl_xor(a1, off);
    a2 += __shfl_xor(a2, off); a3 += __shfl_xor(a3, off);
  }
  if (lane == 0) {
    er[nid * 4 + 0] = a0; er[nid * 4 + 1] = a1;
    er[nid * 4 + 2] = a2; er[nid * 4 + 3] = a3;
  }
}

// ================== bucketed CSR build ==================
// buckets of 1024 dsts; layout: rel0 (cites, Np): buckets [0,NBC),
// rel1 (writes, Np): [NBC,2*NBC), rel2 (written, Na): [2*NBC, 2*NBC+NBA).
// packed staging word: src (18 bits) | dstLow10 << 18.

__global__ __launch_bounds__(256) void zero3(int* p, int n) {
  int i = blockIdx.x * 256 + threadIdx.x;
  if (i < n) p[i] = 0;
}

// per-block LDS bucket histogram -> few global atomics
__global__ __launch_bounds__(256) void p1hist(
    const int* __restrict__ dC, const int* __restrict__ dW, const int* __restrict__ dR,
    int E, int NBC, int* __restrict__ bcnt)
{
  int nbE = (E + 4095) >> 12;
  int bi = blockIdx.x, rel = bi / nbE, ch = bi - rel * nbE;
  const int* d = rel == 0 ? dC : (rel == 1 ? dW : dR);
  int rbase = rel * NBC;
  int e0 = ch << 12, e1 = min(E, e0 + 4096);
  __shared__ int cnt[128];
  int t = threadIdx.x;
  if (t < 128) cnt[t] = 0;
  __syncthreads();
  for (int e = e0 + t; e < e1; e += 256) atomicAdd(&cnt[d[e] >> 10], 1);
  __syncthreads();
  if (t < 128) { int n = cnt[t]; if (n) atomicAdd(&bcnt[rbase + t], n); }
}

// exclusive scan of bucket counts -> bases + cursors (nb <= 1024)
__global__ __launch_bounds__(1024) void bscan(
    const int* __restrict__ bcnt, int* __restrict__ bbase, int* __restrict__ gcur, int nb)
{
  __shared__ int sm[1024];
  int t = threadIdx.x;
  int v = (t < nb) ? bcnt[t] : 0;
  sm[t] = v; __syncthreads();
  for (int off = 1; off < 1024; off <<= 1) {
    int add = (t >= off) ? sm[t - off] : 0;
    __syncthreads();
    sm[t] += add;
    __syncthreads();
  }
  if (t < nb) { int e = sm[t] - v; bbase[t] = e; gcur[t] = e; }
}

// scatter edges into bucket-contiguous staging; one global atomic per (block,bucket);
// each (block,bucket) run is contiguous -> L2-merged writes
__global__ __launch_bounds__(256) void p1scat(
    const int* __restrict__ sC, const int* __restrict__ dC,
    const int* __restrict__ sW, const int* __restrict__ dW,
    const int* __restrict__ sR, const int* __restrict__ dR,
    int E, int NBC, int* __restrict__ gcur, u32* __restrict__ stage3)
{
  int nbE = (E + 4095) >> 12;
  int bi = blockIdx.x, rel = bi / nbE, ch = bi - rel * nbE;
  const int *s, *d;
  if (rel == 0) { s = sC; d = dC; }
  else if (rel == 1) { s = sW; d = dW; }
  else { s = sR; d = dR; }
  int rbase = rel * NBC;
  int e0 = ch << 12, e1 = min(E, e0 + 4096);
  __shared__ int cnt[128], cur[128], gpos[128];
  int t = threadIdx.x;
  if (t < 128) { cnt[t] = 0; cur[t] = 0; }
  __syncthreads();
  for (int e = e0 + t; e < e1; e += 256) atomicAdd(&cnt[d[e] >> 10], 1);
  __syncthreads();
  if (t < 128) { int n = cnt[t]; gpos[t] = n ? atomicAdd(&gcur[rbase + t], n) : 0; }
  __syncthreads();
  for (int e = e0 + t; e < e1; e += 256) {
    int dd = d[e], b = dd >> 10;
    int slot = atomicAdd(&cur[b], 1);
    stage3[gpos[b] + slot] = (u32)(s[e] & 0x3FFFF) | ((u32)(dd & 1023) << 18);
  }
}

// per-bucket fine counting sort: produces rp + srcs (replaces scans + fill)
__global__ __launch_bounds__(256) void p2fine(
    const u32* __restrict__ stage3, const int* __restrict__ bcnt, const int* __restrict__ bbase,
    int* __restrict__ rpC, int* __restrict__ rpW, int* __restrict__ rpR,
    int* __restrict__ srcsC, int* __restrict__ srcsW, int* __restrict__ srcsR,
    int E, int Np, int Na, int NBC)
{
  int bid = blockIdx.x, t = threadIdx.x;
  int rel, b, Nrel; int* rp; int* srcs;
  if (bid < NBC)          { rel = 0; b = bid;            Nrel = Np; rp = rpC; srcs = srcsC; }
  else if (bid < 2 * NBC) { rel = 1; b = bid - NBC;      Nrel = Np; rp = rpW; srcs = srcsW; }
  else                    { rel = 2; b = bid - 2 * NBC;  Nrel = Na; rp = rpR; srcs = srcsR; }
  int base = bbase[bid], cnt = bcnt[bid];
  int csrbase = base - rel * E;
  int dstbase = b << 10;
  int ndst = Nrel - dstbase; if (ndst > 1024) ndst = 1024;
  __shared__ int h[1024], cur[1024], tmp[256];
  for (int i = t; i < 1024; i += 256) h[i] = 0;
  __syncthreads();
  for (int i = t; i < cnt; i += 256) atomicAdd(&h[stage3[base + i] >> 18], 1);
  __syncthreads();
  // exclusive scan over 1024 via 4-per-thread + 256-scan
  int s4 = h[4 * t] + h[4 * t + 1] + h[4 * t + 2] + h[4 * t + 3];
  tmp[t] = s4; __syncthreads();
  for (int off = 1; off < 256; off <<= 1) {
    int add = (t >= off) ? tmp[t - off] : 0;
    __syncthreads();
    tmp[t] += add;
    __syncthreads();
  }
  int run = tmp[t] - s4;
#pragma unroll
  for (int j = 0; j < 4; ++j) { int hv = h[4 * t + j]; cur[4 * t + j] = run; run += hv; }
  __syncthreads();
  for (int d = t; d < ndst; d += 256) rp[dstbase + d] = csrbase + cur[d];
  if (bid == 0 && t == 0) { rpC[Np] = E; rpW[Np] = E; rpR[Na] = E; }
  __syncthreads();
  for (int i = t; i < cnt; i += 256) {
    u32 w = stage3[base + i];
    int lp = atomicAdd(&cur[w >> 18], 1);
    srcs[csrbase + lp] = (int)(w & 0x3FFFF);
  }
}

// ---- softmax-agg helpers; packed f32 accumulate ----
static __device__ __forceinline__ void pk2(float2& a, unsigned int u, float w) {
  union { unsigned int i; float f; } lo, hi;
  lo.i = u << 16; hi.i = u & 0xffff0000u;
  a.x += w * lo.f;
  a.y += w * hi.f;
}
static __device__ __forceinline__ void edge1(
    int sid, int sl, int hh, const float* __restrict__ el, float ern,
    const u16* __restrict__ fs, float2* acc2, float& sw)
{
  float v = el[(size_t)sid * 4 + hh] + ern;
  uint4 r = *(const uint4*)(fs + (size_t)sid * 256 + sl * 8);
  v = v > 0.f ? v : 0.2f * v;
  float w = __expf(v);
  sw += w;
  pk2(acc2[0], r.x, w); pk2(acc2[1], r.y, w);
  pk2(acc2[2], r.z, w); pk2(acc2[3], r.w, w);
}
static __device__ __forceinline__ void edge4(
    int sid0, int sid1, int sid2, int sid3, int sl, int hh,
    const float* __restrict__ el, float ern, const u16* __restrict__ fs,
    float2* acc2, float& sw)
{
  float v0 = el[(size_t)sid0 * 4 + hh] + ern;
  float v1 = el[(size_t)sid1 * 4 + hh] + ern;
  float v2 = el[(size_t)sid2 * 4 + hh] + ern;
  float v3 = el[(size_t)sid3 * 4 + hh] + ern;
  uint4 r0 = *(const uint4*)(fs + (size_t)sid0 * 256 + sl * 8);
  uint4 r1 = *(const uint4*)(fs + (size_t)sid1 * 256 + sl * 8);
  uint4 r2 = *(const uint4*)(fs + (size_t)sid2 * 256 + sl * 8);
  uint4 r3 = *(const uint4*)(fs + (size_t)sid3 * 256 + sl * 8);
  v0 = v0 > 0.f ? v0 : 0.2f * v0;
  v1 = v1 > 0.f ? v1 : 0.2f * v1;
  v2 = v2 > 0.f ? v2 : 0.2f * v2;
  v3 = v3 > 0.f ? v3 : 0.2f * v3;
  float w0 = __expf(v0), w1 = __expf(v1), w2 = __expf(v2), w3 = __expf(v3);
  sw += (w0 + w1) + (w2 + w3);
  pk2(acc2[0], r0.x, w0); pk2(acc2[1], r0.y, w0);
  pk2(acc2[2], r0.z, w0); pk2(acc2[3], r0.w, w0);
  pk2(acc2[0], r1.x, w1); pk2(acc2[1], r1.y, w1);
  pk2(acc2[2], r1.z, w1); pk2(acc2[3], r1.w, w1);
  pk2(acc2[0], r2.x, w2); pk2(acc2[1], r2.y, w2);
  pk2(acc2[2], r2.z, w2); pk2(acc2[3], r2.w, w2);
  pk2(acc2[0], r3.x, w3); pk2(acc2[1], r3.y, w3);
  pk2(acc2[2], r3.z, w3); pk2(acc2[3], r3.w, w3);
}

// ---- paper-dst: wave per dst; half-wave 0 = rel cites, half-wave 1 = rel writes
// (both relations' load chains in flight concurrently); 4-deep edge unroll ----
__global__ __launch_bounds__(256) void agg_paper(
    const int* __restrict__ rp0, const int* __restrict__ srcs0,
    const float* __restrict__ el0, const float* __restrict__ er0,
    const u16* __restrict__ fs0,
    const int* __restrict__ rp1, const int* __restrict__ srcs1,
    const float* __restrict__ el1, const float* __restrict__ er1,
    const u16* __restrict__ fs1,
    const float* __restrict__ bias0, const float* __restrict__ bias1,
    u16* __restrict__ out, int Nd, int relu)
{
  int nid = blockIdx.x * 4 + (threadIdx.x >> 6);
  if (nid >= Nd) return;
  int lane = threadIdx.x & 63;
  int half = lane >> 5, sl = lane & 31, hh = sl >> 3;
  const int* rp     = half ? rp1 : rp0;
  const int* srcs   = half ? srcs1 : srcs0;
  const float* el   = half ? el1 : el0;
  const float* er   = half ? er1 : er0;
  const u16* fs     = half ? fs1 : fs0;
  float ern = er[(size_t)nid * 4 + hh];
  int s0 = rp[nid], s1 = rp[nid + 1];
  float2 acc2[4] = {{0.f,0.f},{0.f,0.f},{0.f,0.f},{0.f,0.f}};
  float sw = 0.f;
  int i = s0;
  for (; i + 3 < s1; i += 4)
    edge4(srcs[i], srcs[i + 1], srcs[i + 2], srcs[i + 3], sl, hh, el, ern, fs, acc2, sw);
  for (; i < s1; ++i)
    edge1(srcs[i], sl, hh, el, ern, fs, acc2, sw);
  // per-relation (per-half) normalize, then sum the two relations across halves
  float inv = sw > 0.f ? 1.f / sw : 0.f;
  float o[8];
#pragma unroll
  for (int k = 0; k < 4; ++k) {
    o[2 * k]     = acc2[k].x * inv;
    o[2 * k + 1] = acc2[k].y * inv;
  }
#pragma unroll
  for (int j = 0; j < 8; ++j) o[j] += __shfl_xor(o[j], 32);
  if (half == 0) {
    const float* bp0 = bias0 + sl * 8;
    const float* bp1 = bias1 + sl * 8;
    bf16x8 r;
#pragma unroll
    for (int j = 0; j < 8; ++j) {
      float v = o[j] + bp0[j] + bp1[j];
      if (relu) v = fmaxf(v, 0.f);
      r[j] = (short)f2bf(v);
    }
    *(bf16x8*)(out + (size_t)nid * 256 + sl * 8) = r;
  }
}

// ---- author-dst: rel written; half-waves split edges, 4-deep unroll ----
__global__ __launch_bounds__(256) void agg_author(
    const int* __restrict__ rp0, const int* __restrict__ srcs0,
    const float* __restrict__ el0, const float* __restrict__ er0,
    const u16* __restrict__ fs0,
    const float* __restrict__ bias0, u16* __restrict__ out, int Nd, int relu)
{
  int nid = blockIdx.x * 4 + (threadIdx.x >> 6);
  if (nid >= Nd) return;
  int lane = threadIdx.x & 63;
  int half = lane >> 5, sl = lane & 31, hh = sl >> 3;
  float ern = er0[(size_t)nid * 4 + hh];
  int s0 = rp0[nid], s1 = rp0[nid + 1];
  float2 acc2[4] = {{0.f,0.f},{0.f,0.f},{0.f,0.f},{0.f,0.f}};
  float sw = 0.f;
  int i = s0 + half;
  for (; i + 6 < s1; i += 8)
    edge4(srcs0[i], srcs0[i + 2], srcs0[i + 4], srcs0[i + 6], sl, hh, el0, ern, fs0, acc2, sw);
  for (; i < s1; i += 2)
    edge1(srcs0[i], sl, hh, el0, ern, fs0, acc2, sw);
  sw += __shfl_xor(sw, 32);
  float inv = sw > 0.f ? 1.f / sw : 0.f;
  float o[8];
#pragma unroll
  for (int k = 0; k < 4; ++k) {
    o[2 * k]     = (acc2[k].x + __shfl_xor(acc2[k].x, 32)) * inv;
    o[2 * k + 1] = (acc2[k].y + __shfl_xor(acc2[k].y, 32)) * inv;
  }
  if (half == 0) {
    const float* bp0 = bias0 + sl * 8;
    bf16x8 r;
#pragma unroll
    for (int j = 0; j < 8; ++j) {
      float v = o[j] + bp0[j];
      if (relu) v = fmaxf(v, 0.f);
      r[j] = (short)f2bf(v);
    }
    *(bf16x8*)(out + (size_t)nid * 256 + sl * 8) = r;
  }
}

static inline int cdiv(int a, int b) { return (a + b - 1) / b; }

extern "C" void kernel_launch(void* const* d_in, const int* in_sizes, int n_in,
                              void* d_out, int out_size, void* d_ws, size_t ws_size,
                              hipStream_t stream)
{
  const float* xp   = (const float*)d_in[0];
  const float* xa   = (const float*)d_in[1];
  const float* W0   = (const float*)d_in[2];   // [3][128][256]
  const float* al0  = (const float*)d_in[3];   // [3][4][64]
  const float* ar0  = (const float*)d_in[4];
  const float* b0   = (const float*)d_in[5];   // [3][256]
  const float* W1   = (const float*)d_in[6];   // [3][256][256]
  const float* al1  = (const float*)d_in[7];
  const float* ar1  = (const float*)d_in[8];
  const float* b1   = (const float*)d_in[9];
  const float* linw = (const float*)d_in[10];  // [256][192]
  const float* linb = (const float*)d_in[11];  // [192]
  const int* srcC = (const int*)d_in[12];
  const int* dstC = (const int*)d_in[13];
  const int* srcW = (const int*)d_in[14];
  const int* dstW = (const int*)d_in[15];
  const int* srcR = (const int*)d_in[16];
  const int* dstR = (const int*)d_in[17];
  float* out = (float*)d_out;

  const int Np = in_sizes[0] / 128;
  const int Na = in_sizes[1] / 128;
  const int E  = in_sizes[12];

  char* base = (char*)d_ws;
  size_t off = 0;
  auto alloc = [&](size_t bytes) -> void* {
    void* r = base + off;
    off += (bytes + 255) & ~(size_t)255;
    return r;
  };
  u16* Wt0  = (u16*)alloc((size_t)3 * 256 * 128 * 2);   // [r][n=256][k=128] bf16
  u16* Wt1  = (u16*)alloc((size_t)3 * 256 * 256 * 2);   // [r][n=256][k=256] bf16
  u16* Wtl  = (u16*)alloc((size_t)192 * 256 * 2);       // [n=192][k=256] bf16
  float* wr01 = (float*)alloc(128 * 4 * 4);
  float* wr02 = (float*)alloc(128 * 4 * 4);
  float* wr11 = (float*)alloc(256 * 4 * 4);
  float* wr12 = (float*)alloc(256 * 4 * 4);
  u16* xpb  = (u16*)alloc((size_t)Np * 128 * 2);
  u16* xab  = (u16*)alloc((size_t)Na * 128 * 2);
  u16* fs0p = (u16*)alloc((size_t)Np * 256 * 2);
  u16* fs1a = (u16*)alloc((size_t)Na * 256 * 2);
  u16* fs2p = (u16*)alloc((size_t)Np * 256 * 2);
  u16* h1p  = (u16*)alloc((size_t)Np * 256 * 2);
  u16* h1a  = (u16*)alloc((size_t)Na * 256 * 2);
  float* el0 = (float*)alloc((size_t)Np * 4 * 4);
  float* er0 = (float*)alloc((size_t)Np * 4 * 4);
  float* el1 = (float*)alloc((size_t)Na * 4 * 4);
  float* er1 = (float*)alloc((size_t)Np * 4 * 4);
  float* el2 = (float*)alloc((size_t)Np * 4 * 4);
  float* er2 = (float*)alloc((size_t)Na * 4 * 4);
  int* rpC  = (int*)alloc((size_t)(Np + 1) * 4);
  int* rpW  = (int*)alloc((size_t)(Np + 1) * 4);
  int* rpR  = (int*)alloc((size_t)(Na + 1) * 4);
  int* srcsC = (int*)alloc((size_t)E * 4);
  int* srcsW = (int*)alloc((size_t)E * 4);
  int* srcsR = (int*)alloc((size_t)E * 4);
  int* bcnt  = (int*)alloc(1024 * 4);
  int* bbase = (int*)alloc(1024 * 4);
  int* gcur  = (int*)alloc(1024 * 4);
  // staging for bucketed sort aliases fs0p (dead until first gemm, 6MB << 51MB)
  u32* stage3 = (u32*)fs0p;

  // ---- input conversion + weight prep ----
  cvt2<<<cdiv(Np * 32 + Na * 32, 256), 256, 0, stream>>>(xp, xa, xpb, xab, Np * 32, Na * 32);
  transpose3<<<cdiv(3 * 128 * 256, 256), 256, 0, stream>>>(W0, Wt0, 3, 128, 256);
  transpose3<<<cdiv(3 * 256 * 256, 256), 256, 0, stream>>>(W1, Wt1, 3, 256, 256);
  transpose3<<<cdiv(256 * 192, 256), 256, 0, stream>>>(linw, Wtl, 1, 256, 192);
  build_wr2<<<cdiv(2 * 128 * 4, 256), 256, 0, stream>>>(W0 + 32768, W0 + 65536,
                                                        ar0 + 256, ar0 + 512, wr01, wr02, 128);
  build_wr2<<<cdiv(2 * 256 * 4, 256), 256, 0, stream>>>(W1 + 65536, W1 + 131072,
                                                        ar1 + 256, ar1 + 512, wr11, wr12, 256);

  // ---- bucketed CSR build ----
  const int NBC = cdiv(Np, 1024);            // paper buckets (per relation)
  const int NBA = cdiv(Na, 1024);            // author buckets
  const int NBtot = 2 * NBC + NBA;
  const int nbE = cdiv(E, 4096);
  zero3<<<cdiv(NBtot, 256), 256, 0, stream>>>(bcnt, NBtot);
  p1hist<<<3 * nbE, 256, 0, stream>>>(dstC, dstW, dstR, E, NBC, bcnt);
  bscan<<<1, 1024, 0, stream>>>(bcnt, bbase, gcur, NBtot);
  p1scat<<<3 * nbE, 256, 0, stream>>>(srcC, dstC, srcW, dstW, srcR, dstR,
                                      E, NBC, gcur, stage3);
  p2fine<<<NBtot, 256, 0, stream>>>(stage3, bcnt, bbase, rpC, rpW, rpR,
                                    srcsC, srcsW, srcsR, E, Np, Na, NBC);

  const int nblkP = cdiv(Np, 64), nblkA = cdiv(Na, 64);

  auto layer = [&](const u16* inP, const u16* inA, const u16* WtL, int K,
                   const float* alL, const float* arL,
                   const float* wr1, const float* wr2, const float* bL,
                   u16* outP, u16* outA, int relu) {
    if (K == 128) {
      gemm3<128><<<2 * nblkP + nblkA, 256, 0, stream>>>(
          inP, inA, WtL, fs0p, fs1a, fs2p, alL, arL,
          el0, el1, el2, er0, Np, Na, nblkP, nblkA);
    } else {
      gemm3<256><<<2 * nblkP + nblkA, 256, 0, stream>>>(
          inP, inA, WtL, fs0p, fs1a, fs2p, alL, arL,
          el0, el1, el2, er0, Np, Na, nblkP, nblkA);
    }
    er_wr2<<<cdiv(Np, 4) + cdiv(Na, 4), 256, 0, stream>>>(inP, inA, wr1, wr2, er1, er2, Np, Na, K);
    agg_paper<<<cdiv(Np, 4), 256, 0, stream>>>(rpC, srcsC, el0, er0, fs0p,
                                               rpW, srcsW, el1, er1, fs1a,
                                               bL, bL + 256, outP, Np, relu);
    agg_author<<<cdiv(Na, 4), 256, 0, stream>>>(rpR, srcsR, el2, er2, fs2p,
                                                bL + 512, outA, Na, relu);
  };

  layer(xpb, xab, Wt0, 128, al0, ar0, wr01, wr02, b0, h1p, h1a, 1);
  layer(h1p, h1a, Wt1, 256, al1, ar1, wr11, wr12, b1, h1p, h1a, 0);

  // ---- final linear ----
  gemm_rb<256, 3><<<dim3(cdiv(Np, 64)), 256, 0, stream>>>(
      h1p, Wtl, nullptr, out, linb, nullptr, nullptr, nullptr, nullptr, Np);
}

// Round 7
// 789.599 us; speedup vs baseline: 1.2034x; 1.0045x over previous
//
#include <hip/hip_runtime.h>

typedef unsigned short u16;
typedef unsigned int u32;
typedef __attribute__((ext_vector_type(8))) short bf16x8;
typedef __attribute__((ext_vector_type(4))) float f32x4;

static __device__ __forceinline__ float bf2f(u16 u) {
  union { unsigned int i; float f; } v; v.i = ((unsigned int)u) << 16; return v.f;
}
static __device__ __forceinline__ u16 f2bf(float f) {
  union { float f; unsigned int i; } v; v.f = f;
  unsigned int i = v.i;
  return (u16)((i + 0x7FFFu + ((i >> 16) & 1u)) >> 16);
}

// async global->LDS, 16B per lane (guide §5: width=16 is the fast path)
static __device__ __forceinline__ void gl16(const u16* g, u16* l) {
  __builtin_amdgcn_global_load_lds(
      (const __attribute__((address_space(1))) unsigned int*)g,
      (__attribute__((address_space(3))) unsigned int*)l, 16, 0, 0);
}

// ---- convert f32 -> bf16 for both inputs in one launch ----
__global__ __launch_bounds__(256) void cvt2(const float* __restrict__ a, const float* __restrict__ b,
                                            u16* __restrict__ da, u16* __restrict__ db,
                                            int n4a, int n4b)
{
  int i = blockIdx.x * 256 + threadIdx.x;
  const float* s; u16* d; int j;
  if (i < n4a) { s = a; d = da; j = i; }
  else { j = i - n4a; if (j >= n4b) return; s = b; d = db; }
  float4 v = ((const float4*)s)[j];
  ushort4 r;
  r.x = f2bf(v.x); r.y = f2bf(v.y); r.z = f2bf(v.z); r.w = f2bf(v.w);
  ((ushort4*)d)[j] = r;
}

// ---- transpose R chunks: dst[r][n*K+k] (bf16) = src[r][k*N+n] (f32) ----
__global__ __launch_bounds__(256) void transpose3(const float* __restrict__ src,
                                                  u16* __restrict__ dst, int R, int K, int N)
{
  int idx = blockIdx.x * 256 + threadIdx.x;
  if (idx >= R * K * N) return;
  int r = idx / (K * N), rem = idx - r * K * N;
  int k = rem / N, n = rem - k * N;
  dst[(size_t)r * N * K + (size_t)n * K + k] = f2bf(src[idx]);
}

// ---- wr for two relations of one layer in one launch ----
__global__ __launch_bounds__(256) void build_wr2(
    const float* __restrict__ Wa, const float* __restrict__ Wb,
    const float* __restrict__ ara, const float* __restrict__ arb,
    float* __restrict__ wra, float* __restrict__ wrb, int K)
{
  int idx = blockIdx.x * 256 + threadIdx.x;
  if (idx >= 2 * K * 4) return;
  int sel = idx / (K * 4), rem = idx - sel * K * 4;
  int k = rem >> 2, h = rem & 3;
  const float* W = sel ? Wb : Wa;
  const float* ar = sel ? arb : ara;
  float s = 0.f;
  for (int d = 0; d < 64; ++d)
    s += W[(size_t)k * 256 + h * 64 + d] * ar[h * 64 + d];
  (sel ? wrb : wra)[rem] = s;
}

// ======== GEMM core: LDS ring (single barrier per K-step), counted vmcnt,
// B prefetched one step ahead, fused el/er epilogue. MFMA order identical to
// round-4 -> bit-identical results. ========
template<int K, int NTW>
static __device__ __forceinline__ void gemm_core(
    const u16* __restrict__ X, const u16* __restrict__ Wt,
    u16* __restrict__ out16, float* __restrict__ out32,
    const float* __restrict__ bias,
    const float* __restrict__ al4, const float* __restrict__ ar4,
    float* __restrict__ el, float* __restrict__ er, int M, int mblk,
    u16 (*As)[64 * 64])
{
  constexpr int NS = K / 64;                 // 64-wide K stages
  constexpr int RING = (NS >= 3) ? 3 : 2;    // LDS ring depth
  const int N = NTW * 16 * 4;
  const int t = threadIdx.x;
  const int wave = t >> 6, lane = t & 63;
  const int quad = lane >> 4, l16 = lane & 15;
  const int mbase = mblk * 64;
  const int nbase = wave * (NTW * 16);

  // staging: thread t covers rows r0 (round 0) and r1 (round 1), 16B each.
  // physical chunk = t&7; source chunk = (t&7) ^ (row&7)  (XOR involution)
  int r0 = t >> 3, r1 = 32 + (t >> 3);
  int c0 = (t & 7) ^ (r0 & 7);
  int c1 = (t & 7) ^ (r1 & 7);
  int rr0 = mbase + r0; if (rr0 >= M) rr0 = M - 1;   // clamp tail (stores guarded)
  int rr1 = mbase + r1; if (rr1 >= M) rr1 = M - 1;
  const u16* g0 = X + (size_t)rr0 * K + c0 * 8;
  const u16* g1 = X + (size_t)rr1 * K + c1 * 8;

  const u16* wp = Wt + (size_t)(nbase + l16) * K + quad * 8;

  f32x4 acc[4][NTW];
#pragma unroll
  for (int mt = 0; mt < 4; ++mt)
#pragma unroll
    for (int nt = 0; nt < NTW; ++nt) acc[mt][nt] = (f32x4){0.f, 0.f, 0.f, 0.f};

  bf16x8 bb[2][NTW];                          // one stage of B, prefetched

  auto stage_a = [&](int s, int b) {
    gl16(g0 + s * 64, &As[b][t * 8]);
    gl16(g1 + s * 64, &As[b][2048 + t * 8]);
  };
  auto load_b = [&](int s) {
#pragma unroll
    for (int kk = 0; kk < 2; ++kk)
#pragma unroll
      for (int nt = 0; nt < NTW; ++nt)
        bb[kk][nt] = *(const bf16x8*)(wp + (size_t)nt * 16 * K + s * 64 + kk * 32);
  };

  // prologue FIFO: A0 (2) | B0 (2*NTW) | A1 (2) — order pinned
  stage_a(0, 0);
  __builtin_amdgcn_sched_barrier(0);
  load_b(0);
  __builtin_amdgcn_sched_barrier(0);
  if (NS > 1) stage_a(1, 1);
  __builtin_amdgcn_sched_barrier(0);

  const int sw = (l16 & 7) << 3;              // u16-unit read swizzle
#pragma unroll
  for (int ks = 0; ks < NS; ++ks) {
    // steady state: A(ks)+B(ks) done; A(ks+1) (2 ops) stays in flight
    if (ks + 1 < NS) asm volatile("s_waitcnt vmcnt(2)" ::: "memory");
    else             asm volatile("s_waitcnt vmcnt(0)" ::: "memory");
    __builtin_amdgcn_s_barrier();             // all waves' A(ks) arrived; also
                                              // guarantees ring buf (ks+2)%RING
                                              // (read at ks-1) is free to overwrite
    __builtin_amdgcn_sched_barrier(0);
    const u16* Ab = As[ks % RING];
#pragma unroll
    for (int kk = 0; kk < 2; ++kk) {
      bf16x8 a[4];
#pragma unroll
      for (int mt = 0; mt < 4; ++mt)
        a[mt] = *(const bf16x8*)(Ab + (mt * 16 + l16) * 64 + ((kk * 32 + quad * 8) ^ sw));
#pragma unroll
      for (int mt = 0; mt < 4; ++mt)
#pragma unroll
        for (int nt = 0; nt < NTW; ++nt)
          acc[mt][nt] = __builtin_amdgcn_mfma_f32_16x16x32_bf16(a[mt], bb[kk][nt], acc[mt][nt], 0, 0, 0);
    }
    // FIFO per step: B(ks+1) then A(ks+2) — keeps vmcnt(2) = {A(ks+1) only}
    if (ks + 1 < NS) load_b(ks + 1);          // WAR on bb after its MFMAs
    __builtin_amdgcn_sched_barrier(0);
    if (ks + 2 < NS) {
      stage_a(ks + 2, (ks + 2) % RING);
      __builtin_amdgcn_sched_barrier(0);
    }
  }

#pragma unroll
  for (int mt = 0; mt < 4; ++mt)
#pragma unroll
    for (int nt = 0; nt < NTW; ++nt) {
      int col = nbase + nt * 16 + l16;
      float bv = bias ? bias[col] : 0.f;
#pragma unroll
      for (int r = 0; r < 4; ++r) {
        int row = mbase + mt * 16 + quad * 4 + r;
        if (row < M) {
          float v = acc[mt][nt][r] + bv;
          if (out32) out32[(size_t)row * N + col] = v;
          else       out16[(size_t)row * N + col] = f2bf(v);
        }
      }
    }
  // fused el/er (all shfls wave-uniform; only stores guarded)
  if (al4 != nullptr) {
    float alv[NTW], arv[NTW];
#pragma unroll
    for (int nt = 0; nt < NTW; ++nt) {
      alv[nt] = al4[wave * 64 + nt * 16 + l16];
      arv[nt] = ar4 ? ar4[wave * 64 + nt * 16 + l16] : 0.f;
    }
#pragma unroll
    for (int mt = 0; mt < 4; ++mt) {
#pragma unroll
      for (int r = 0; r < 4; ++r) {
        float p = 0.f, q = 0.f;
#pragma unroll
        for (int nt = 0; nt < NTW; ++nt) {
          p += acc[mt][nt][r] * alv[nt];
          q += acc[mt][nt][r] * arv[nt];
        }
#pragma unroll
        for (int off = 1; off < 16; off <<= 1) {
          p += __shfl_xor(p, off);
          q += __shfl_xor(q, off);
        }
        int row = mbase + mt * 16 + quad * 4 + r;
        if (l16 == 0 && row < M) {
          el[row * 4 + wave] = p;
          if (ar4) er[row * 4 + wave] = q;
        }
      }
    }
  }
}

// ---- standalone GEMM (final linear) ----
template<int K, int NTW>
__global__ __launch_bounds__(256, 4) void gemm_rb(
    const u16* __restrict__ X, const u16* __restrict__ Wt,
    u16* __restrict__ out16, float* __restrict__ out32,
    const float* __restrict__ bias,
    const float* __restrict__ al4, const float* __restrict__ ar4,
    float* __restrict__ el, float* __restrict__ er, int M)
{
  constexpr int RING = (K / 64 >= 3) ? 3 : 2;
  __shared__ __align__(16) u16 As[RING][64 * 64];
  gemm_core<K, NTW>(X, Wt, out16, out32, bias, al4, ar4, el, er, M, blockIdx.x, As);
}

// ---- fused 3-relation layer GEMM: one launch covers rel0 (paper), rel1 (author),
// rel2 (paper). Block id decodes relation; per-relation pointers selected uniformly. ----
template<int K>
__global__ __launch_bounds__(256, 4) void gemm3(
    const u16* __restrict__ Xp, const u16* __restrict__ Xa,
    const u16* __restrict__ Wt,          // [3][256][K]
    u16* __restrict__ fs0, u16* __restrict__ fs1, u16* __restrict__ fs2,
    const float* __restrict__ al,        // [3][256]
    const float* __restrict__ ar0v,      // [256], rel0 only
    float* __restrict__ el0, float* __restrict__ el1, float* __restrict__ el2,
    float* __restrict__ er0,
    int Np, int Na, int nblkP, int nblkA)
{
  constexpr int RING = (K / 64 >= 3) ? 3 : 2;
  __shared__ __align__(16) u16 As[RING][64 * 64];
  int bid = blockIdx.x;
  int rel, lb;
  if (bid < nblkP)              { rel = 0; lb = bid; }
  else if (bid < nblkP + nblkA) { rel = 1; lb = bid - nblkP; }
  else                          { rel = 2; lb = bid - nblkP - nblkA; }
  const u16* X  = (rel == 1) ? Xa : Xp;
  const int  M  = (rel == 1) ? Na : Np;
  const u16* W  = Wt + (size_t)rel * 256 * K;
  u16* out      = rel == 0 ? fs0 : (rel == 1 ? fs1 : fs2);
  const float* al4 = al + rel * 256;
  const float* ar4 = (rel == 0) ? ar0v : nullptr;
  float* el     = rel == 0 ? el0 : (rel == 1 ? el1 : el2);
  float* er     = (rel == 0) ? er0 : nullptr;
  gemm_core<K, 4>(X, W, out, nullptr, nullptr, al4, ar4, el, er, M, lb, As);
}

// ---- er[n][h] = sum_k X[n][k](bf16) * wr[k][h]; paper + author in one launch ----
__global__ __launch_bounds__(256) void er_wr2(
    const u16* __restrict__ Xp, const u16* __restrict__ Xa,
    const float* __restrict__ wrp, const float* __restrict__ wra,
    float* __restrict__ erp, float* __restrict__ era, int Np, int Na, int K)
{
  int nblkP = (Np + 3) / 4;
  int bid = blockIdx.x;
  const u16* X; const float* wr; float* er; int nid, Nn;
  if (bid < nblkP) { X = Xp; wr = wrp; er = erp; Nn = Np; nid = bid * 4 + (threadIdx.x >> 6); }
  else { X = Xa; wr = wra; er = era; Nn = Na; nid = (bid - nblkP) * 4 + (threadIdx.x >> 6); }
  if (nid >= Nn) return;
  int lane = threadIdx.x & 63;
  float a0 = 0.f, a1 = 0.f, a2 = 0.f, a3 = 0.f;
  for (int k = lane; k < K; k += 64) {
    float xv = bf2f(X[(size_t)nid * K + k]);
    const float* w = wr + k * 4;
    a0 += xv * w[0]; a1 += xv * w[1]; a2 += xv * w[2]; a3 += xv * w[3];
  }
  for (int off = 1; off < 64; off <<= 1) {
    a0 += __shfl_xor(a0, off); a1 += __shfl_xor(a1, off);
    a2 += __shfl_xor(a2, off); a3 += __shfl_xor(a3, off);
  }
  if (lane == 0) {
    er[nid * 4 + 0] = a0; er[nid * 4 + 1] = a1;
    er[nid * 4 + 2] = a2; er[nid * 4 + 3] = a3;
  }
}

// ================== bucketed CSR build ==================
// buckets of 1024 dsts; layout: rel0 (cites, Np): buckets [0,NBC),
// rel1 (writes, Np): [NBC,2*NBC), rel2 (written, Na): [2*NBC, 2*NBC+NBA).
// packed staging word: src (18 bits) | dstLow10 << 18.

__global__ __launch_bounds__(256) void zero3(int* p, int n) {
  int i = blockIdx.x * 256 + threadIdx.x;
  if (i < n) p[i] = 0;
}

// per-block LDS bucket histogram -> few global atomics
__global__ __launch_bounds__(256) void p1hist(
    const int* __restrict__ dC, const int* __restrict__ dW, const int* __restrict__ dR,
    int E, int NBC, int* __restrict__ bcnt)
{
  int nbE = (E + 4095) >> 12;
  int bi = blockIdx.x, rel = bi / nbE, ch = bi - rel * nbE;
  const int* d = rel == 0 ? dC : (rel == 1 ? dW : dR);
  int rbase = rel * NBC;
  int e0 = ch << 12, e1 = min(E, e0 + 4096);
  __shared__ int cnt[128];
  int t = threadIdx.x;
  if (t < 128) cnt[t] = 0;
  __syncthreads();
  for (int e = e0 + t; e < e1; e += 256) atomicAdd(&cnt[d[e] >> 10], 1);
  __syncthreads();
  if (t < 128) { int n = cnt[t]; if (n) atomicAdd(&bcnt[rbase + t], n); }
}

// exclusive scan of bucket counts -> bases + cursors (nb <= 1024)
__global__ __launch_bounds__(1024) void bscan(
    const int* __restrict__ bcnt, int* __restrict__ bbase, int* __restrict__ gcur, int nb)
{
  __shared__ int sm[1024];
  int t = threadIdx.x;
  int v = (t < nb) ? bcnt[t] : 0;
  sm[t] = v; __syncthreads();
  for (int off = 1; off < 1024; off <<= 1) {
    int add = (t >= off) ? sm[t - off] : 0;
    __syncthreads();
    sm[t] += add;
    __syncthreads();
  }
  if (t < nb) { int e = sm[t] - v; bbase[t] = e; gcur[t] = e; }
}

// scatter edges into bucket-contiguous staging; one global atomic per (block,bucket);
// each (block,bucket) run is contiguous -> L2-merged writes
__global__ __launch_bounds__(256) void p1scat(
    const int* __restrict__ sC, const int* __restrict__ dC,
    const int* __restrict__ sW, const int* __restrict__ dW,
    const int* __restrict__ sR, const int* __restrict__ dR,
    int E, int NBC, int* __restrict__ gcur, u32* __restrict__ stage3)
{
  int nbE = (E + 4095) >> 12;
  int bi = blockIdx.x, rel = bi / nbE, ch = bi - rel * nbE;
  const int *s, *d;
  if (rel == 0) { s = sC; d = dC; }
  else if (rel == 1) { s = sW; d = dW; }
  else { s = sR; d = dR; }
  int rbase = rel * NBC;
  int e0 = ch << 12, e1 = min(E, e0 + 4096);
  __shared__ int cnt[128], cur[128], gpos[128];
  int t = threadIdx.x;
  if (t < 128) { cnt[t] = 0; cur[t] = 0; }
  __syncthreads();
  for (int e = e0 + t; e < e1; e += 256) atomicAdd(&cnt[d[e] >> 10], 1);
  __syncthreads();
  if (t < 128) { int n = cnt[t]; gpos[t] = n ? atomicAdd(&gcur[rbase + t], n) : 0; }
  __syncthreads();
  for (int e = e0 + t; e < e1; e += 256) {
    int dd = d[e], b = dd >> 10;
    int slot = atomicAdd(&cur[b], 1);
    stage3[gpos[b] + slot] = (u32)(s[e] & 0x3FFFF) | ((u32)(dd & 1023) << 18);
  }
}

// per-bucket fine counting sort: produces rp + srcs (replaces scans + fill)
__global__ __launch_bounds__(256) void p2fine(
    const u32* __restrict__ stage3, const int* __restrict__ bcnt, const int* __restrict__ bbase,
    int* __restrict__ rpC, int* __restrict__ rpW, int* __restrict__ rpR,
    int* __restrict__ srcsC, int* __restrict__ srcsW, int* __restrict__ srcsR,
    int E, int Np, int Na, int NBC)
{
  int bid = blockIdx.x, t = threadIdx.x;
  int rel, b, Nrel; int* rp; int* srcs;
  if (bid < NBC)          { rel = 0; b = bid;            Nrel = Np; rp = rpC; srcs = srcsC; }
  else if (bid < 2 * NBC) { rel = 1; b = bid - NBC;      Nrel = Np; rp = rpW; srcs = srcsW; }
  else                    { rel = 2; b = bid - 2 * NBC;  Nrel = Na; rp = rpR; srcs = srcsR; }
  int base = bbase[bid], cnt = bcnt[bid];
  int csrbase = base - rel * E;
  int dstbase = b << 10;
  int ndst = Nrel - dstbase; if (ndst > 1024) ndst = 1024;
  __shared__ int h[1024], cur[1024], tmp[256];
  for (int i = t; i < 1024; i += 256) h[i] = 0;
  __syncthreads();
  for (int i = t; i < cnt; i += 256) atomicAdd(&h[stage3[base + i] >> 18], 1);
  __syncthreads();
  // exclusive scan over 1024 via 4-per-thread + 256-scan
  int s4 = h[4 * t] + h[4 * t + 1] + h[4 * t + 2] + h[4 * t + 3];
  tmp[t] = s4; __syncthreads();
  for (int off = 1; off < 256; off <<= 1) {
    int add = (t >= off) ? tmp[t - off] : 0;
    __syncthreads();
    tmp[t] += add;
    __syncthreads();
  }
  int run = tmp[t] - s4;
#pragma unroll
  for (int j = 0; j < 4; ++j) { int hv = h[4 * t + j]; cur[4 * t + j] = run; run += hv; }
  __syncthreads();
  for (int d = t; d < ndst; d += 256) rp[dstbase + d] = csrbase + cur[d];
  if (bid == 0 && t == 0) { rpC[Np] = E; rpW[Np] = E; rpR[Na] = E; }
  __syncthreads();
  for (int i = t; i < cnt; i += 256) {
    u32 w = stage3[base + i];
    int lp = atomicAdd(&cur[w >> 18], 1);
    srcs[csrbase + lp] = (int)(w & 0x3FFFF);
  }
}

// ---- softmax-agg helpers; packed f32 accumulate ----
static __device__ __forceinline__ void pk2(float2& a, unsigned int u, float w) {
  union { unsigned int i; float f; } lo, hi;
  lo.i = u << 16; hi.i = u & 0xffff0000u;
  a.x += w * lo.f;
  a.y += w * hi.f;
}
static __device__ __forceinline__ void edge1(
    int sid, int sl, int hh, const float* __restrict__ el, float ern,
    const u16* __restrict__ fs, float2* acc2, float& sw)
{
  float v = el[(size_t)sid * 4 + hh] + ern;
  uint4 r = *(const uint4*)(fs + (size_t)sid * 256 + sl * 8);
  v = v > 0.f ? v : 0.2f * v;
  float w = __expf(v);
  sw += w;
  pk2(acc2[0], r.x, w); pk2(acc2[1], r.y, w);
  pk2(acc2[2], r.z, w); pk2(acc2[3], r.w, w);
}
static __device__ __forceinline__ void edge4(
    int sid0, int sid1, int sid2, int sid3, int sl, int hh,
    const float* __restrict__ el, float ern, const u16* __restrict__ fs,
    float2* acc2, float& sw)
{
  float v0 = el[(size_t)sid0 * 4 + hh] + ern;
  float v1 = el[(size_t)sid1 * 4 + hh] + ern;
  float v2 = el[(size_t)sid2 * 4 + hh] + ern;
  float v3 = el[(size_t)sid3 * 4 + hh] + ern;
  uint4 r0 = *(const uint4*)(fs + (size_t)sid0 * 256 + sl * 8);
  uint4 r1 = *(const uint4*)(fs + (size_t)sid1 * 256 + sl * 8);
  uint4 r2 = *(const uint4*)(fs + (size_t)sid2 * 256 + sl * 8);
  uint4 r3 = *(const uint4*)(fs + (size_t)sid3 * 256 + sl * 8);
  v0 = v0 > 0.f ? v0 : 0.2f * v0;
  v1 = v1 > 0.f ? v1 : 0.2f * v1;
  v2 = v2 > 0.f ? v2 : 0.2f * v2;
  v3 = v3 > 0.f ? v3 : 0.2f * v3;
  float w0 = __expf(v0), w1 = __expf(v1), w2 = __expf(v2), w3 = __expf(v3);
  sw += (w0 + w1) + (w2 + w3);
  pk2(acc2[0], r0.x, w0); pk2(acc2[1], r0.y, w0);
  pk2(acc2[2], r0.z, w0); pk2(acc2[3], r0.w, w0);
  pk2(acc2[0], r1.x, w1); pk2(acc2[1], r1.y, w1);
  pk2(acc2[2], r1.z, w1); pk2(acc2[3], r1.w, w1);
  pk2(acc2[0], r2.x, w2); pk2(acc2[1], r2.y, w2);
  pk2(acc2[2], r2.z, w2); pk2(acc2[3], r2.w, w2);
  pk2(acc2[0], r3.x, w3); pk2(acc2[1], r3.y, w3);
  pk2(acc2[2], r3.z, w3); pk2(acc2[3], r3.w, w3);
}

// ---- paper-dst: wave per dst; half-wave 0 = rel cites, half-wave 1 = rel writes
// (both relations' load chains in flight concurrently); 4-deep edge unroll ----
__global__ __launch_bounds__(256) void agg_paper(
    const int* __restrict__ rp0, const int* __restrict__ srcs0,
    const float* __restrict__ el0, const float* __restrict__ er0,
    const u16* __restrict__ fs0,
    const int* __restrict__ rp1, const int* __restrict__ srcs1,
    const float* __restrict__ el1, const float* __restrict__ er1,
    const u16* __restrict__ fs1,
    const float* __restrict__ bias0, const float* __restrict__ bias1,
    u16* __restrict__ out, int Nd, int relu)
{
  int nid = blockIdx.x * 4 + (threadIdx.x >> 6);
  if (nid >= Nd) return;
  int lane = threadIdx.x & 63;
  int half = lane >> 5, sl = lane & 31, hh = sl >> 3;
  const int* rp     = half ? rp1 : rp0;
  const int* srcs   = half ? srcs1 : srcs0;
  const float* el   = half ? el1 : el0;
  const float* er   = half ? er1 : er0;
  const u16* fs     = half ? fs1 : fs0;
  float ern = er[(size_t)nid * 4 + hh];
  int s0 = rp[nid], s1 = rp[nid + 1];
  float2 acc2[4] = {{0.f,0.f},{0.f,0.f},{0.f,0.f},{0.f,0.f}};
  float sw = 0.f;
  int i = s0;
  for (; i + 3 < s1; i += 4)
    edge4(srcs[i], srcs[i + 1], srcs[i + 2], srcs[i + 3], sl, hh, el, ern, fs, acc2, sw);
  for (; i < s1; ++i)
    edge1(srcs[i], sl, hh, el, ern, fs, acc2, sw);
  // per-relation (per-half) normalize, then sum the two relations across halves
  float inv = sw > 0.f ? 1.f / sw : 0.f;
  float o[8];
#pragma unroll
  for (int k = 0; k < 4; ++k) {
    o[2 * k]     = acc2[k].x * inv;
    o[2 * k + 1] = acc2[k].y * inv;
  }
#pragma unroll
  for (int j = 0; j < 8; ++j) o[j] += __shfl_xor(o[j], 32);
  if (half == 0) {
    const float* bp0 = bias0 + sl * 8;
    const float* bp1 = bias1 + sl * 8;
    bf16x8 r;
#pragma unroll
    for (int j = 0; j < 8; ++j) {
      float v = o[j] + bp0[j] + bp1[j];
      if (relu) v = fmaxf(v, 0.f);
      r[j] = (short)f2bf(v);
    }
    *(bf16x8*)(out + (size_t)nid * 256 + sl * 8) = r;
  }
}

// ---- author-dst: rel written; half-waves split edges, 4-deep unroll ----
__global__ __launch_bounds__(256) void agg_author(
    const int* __restrict__ rp0, const int* __restrict__ srcs0,
    const float* __restrict__ el0, const float* __restrict__ er0,
    const u16* __restrict__ fs0,
    const float* __restrict__ bias0, u16* __restrict__ out, int Nd, int relu)
{
  int nid = blockIdx.x * 4 + (threadIdx.x >> 6);
  if (nid >= Nd) return;
  int lane = threadIdx.x & 63;
  int half = lane >> 5, sl = lane & 31, hh = sl >> 3;
  float ern = er0[(size_t)nid * 4 + hh];
  int s0 = rp0[nid], s1 = rp0[nid + 1];
  float2 acc2[4] = {{0.f,0.f},{0.f,0.f},{0.f,0.f},{0.f,0.f}};
  float sw = 0.f;
  int i = s0 + half;
  for (; i + 6 < s1; i += 8)
    edge4(srcs0[i], srcs0[i + 2], srcs0[i + 4], srcs0[i + 6], sl, hh, el0, ern, fs0, acc2, sw);
  for (; i < s1; i += 2)
    edge1(srcs0[i], sl, hh, el0, ern, fs0, acc2, sw);
  sw += __shfl_xor(sw, 32);
  float inv = sw > 0.f ? 1.f / sw : 0.f;
  float o[8];
#pragma unroll
  for (int k = 0; k < 4; ++k) {
    o[2 * k]     = (acc2[k].x + __shfl_xor(acc2[k].x, 32)) * inv;
    o[2 * k + 1] = (acc2[k].y + __shfl_xor(acc2[k].y, 32)) * inv;
  }
  if (half == 0) {
    const float* bp0 = bias0 + sl * 8;
    bf16x8 r;
#pragma unroll
    for (int j = 0; j < 8; ++j) {
      float v = o[j] + bp0[j];
      if (relu) v = fmaxf(v, 0.f);
      r[j] = (short)f2bf(v);
    }
    *(bf16x8*)(out + (size_t)nid * 256 + sl * 8) = r;
  }
}

static inline int cdiv(int a, int b) { return (a + b - 1) / b; }

extern "C" void kernel_launch(void* const* d_in, const int* in_sizes, int n_in,
                              void* d_out, int out_size, void* d_ws, size_t ws_size,
                              hipStream_t stream)
{
  const float* xp   = (const float*)d_in[0];
  const float* xa   = (const float*)d_in[1];
  const float* W0   = (const float*)d_in[2];   // [3][128][256]
  const float* al0  = (const float*)d_in[3];   // [3][4][64]
  const float* ar0  = (const float*)d_in[4];
  const float* b0   = (const float*)d_in[5];   // [3][256]
  const float* W1   = (const float*)d_in[6];   // [3][256][256]
  const float* al1  = (const float*)d_in[7];
  const float* ar1  = (const float*)d_in[8];
  const float* b1   = (const float*)d_in[9];
  const float* linw = (const float*)d_in[10];  // [256][192]
  const float* linb = (const float*)d_in[11];  // [192]
  const int* srcC = (const int*)d_in[12];
  const int* dstC = (const int*)d_in[13];
  const int* srcW = (const int*)d_in[14];
  const int* dstW = (const int*)d_in[15];
  const int* srcR = (const int*)d_in[16];
  const int* dstR = (const int*)d_in[17];
  float* out = (float*)d_out;

  const int Np = in_sizes[0] / 128;
  const int Na = in_sizes[1] / 128;
  const int E  = in_sizes[12];

  char* base = (char*)d_ws;
  size_t off = 0;
  auto alloc = [&](size_t bytes) -> void* {
    void* r = base + off;
    off += (bytes + 255) & ~(size_t)255;
    return r;
  };
  u16* Wt0  = (u16*)alloc((size_t)3 * 256 * 128 * 2);   // [r][n=256][k=128] bf16
  u16* Wt1  = (u16*)alloc((size_t)3 * 256 * 256 * 2);   // [r][n=256][k=256] bf16
  u16* Wtl  = (u16*)alloc((size_t)192 * 256 * 2);       // [n=192][k=256] bf16
  float* wr01 = (float*)alloc(128 * 4 * 4);
  float* wr02 = (float*)alloc(128 * 4 * 4);
  float* wr11 = (float*)alloc(256 * 4 * 4);
  float* wr12 = (float*)alloc(256 * 4 * 4);
  u16* xpb  = (u16*)alloc((size_t)Np * 128 * 2);
  u16* xab  = (u16*)alloc((size_t)Na * 128 * 2);
  u16* fs0p = (u16*)alloc((size_t)Np * 256 * 2);
  u16* fs1a = (u16*)alloc((size_t)Na * 256 * 2);
  u16* fs2p = (u16*)alloc((size_t)Np * 256 * 2);
  u16* h1p  = (u16*)alloc((size_t)Np * 256 * 2);
  u16* h1a  = (u16*)alloc((size_t)Na * 256 * 2);
  float* el0 = (float*)alloc((size_t)Np * 4 * 4);
  float* er0 = (float*)alloc((size_t)Np * 4 * 4);
  float* el1 = (float*)alloc((size_t)Na * 4 * 4);
  float* er1 = (float*)alloc((size_t)Np * 4 * 4);
  float* el2 = (float*)alloc((size_t)Np * 4 * 4);
  float* er2 = (float*)alloc((size_t)Na * 4 * 4);
  int* rpC  = (int*)alloc((size_t)(Np + 1) * 4);
  int* rpW  = (int*)alloc((size_t)(Np + 1) * 4);
  int* rpR  = (int*)alloc((size_t)(Na + 1) * 4);
  int* srcsC = (int*)alloc((size_t)E * 4);
  int* srcsW = (int*)alloc((size_t)E * 4);
  int* srcsR = (int*)alloc((size_t)E * 4);
  int* bcnt  = (int*)alloc(1024 * 4);
  int* bbase = (int*)alloc(1024 * 4);
  int* gcur  = (int*)alloc(1024 * 4);
  // staging for bucketed sort aliases fs0p (dead until first gemm, 6MB << 51MB)
  u32* stage3 = (u32*)fs0p;

  // ---- input conversion + weight prep ----
  cvt2<<<cdiv(Np * 32 + Na * 32, 256), 256, 0, stream>>>(xp, xa, xpb, xab, Np * 32, Na * 32);
  transpose3<<<cdiv(3 * 128 * 256, 256), 256, 0, stream>>>(W0, Wt0, 3, 128, 256);
  transpose3<<<cdiv(3 * 256 * 256, 256), 256, 0, stream>>>(W1, Wt1, 3, 256, 256);
  transpose3<<<cdiv(256 * 192, 256), 256, 0, stream>>>(linw, Wtl, 1, 256, 192);
  build_wr2<<<cdiv(2 * 128 * 4, 256), 256, 0, stream>>>(W0 + 32768, W0 + 65536,
                                                        ar0 + 256, ar0 + 512, wr01, wr02, 128);
  build_wr2<<<cdiv(2 * 256 * 4, 256), 256, 0, stream>>>(W1 + 65536, W1 + 131072,
                                                        ar1 + 256, ar1 + 512, wr11, wr12, 256);

  // ---- bucketed CSR build ----
  const int NBC = cdiv(Np, 1024);            // paper buckets (per relation)
  const int NBA = cdiv(Na, 1024);            // author buckets
  const int NBtot = 2 * NBC + NBA;
  const int nbE = cdiv(E, 4096);
  zero3<<<cdiv(NBtot, 256), 256, 0, stream>>>(bcnt, NBtot);
  p1hist<<<3 * nbE, 256, 0, stream>>>(dstC, dstW, dstR, E, NBC, bcnt);
  bscan<<<1, 1024, 0, stream>>>(bcnt, bbase, gcur, NBtot);
  p1scat<<<3 * nbE, 256, 0, stream>>>(srcC, dstC, srcW, dstW, srcR, dstR,
                                      E, NBC, gcur, stage3);
  p2fine<<<NBtot, 256, 0, stream>>>(stage3, bcnt, bbase, rpC, rpW, rpR,
                                    srcsC, srcsW, srcsR, E, Np, Na, NBC);

  const int nblkP = cdiv(Np, 64), nblkA = cdiv(Na, 64);

  auto layer = [&](const u16* inP, const u16* inA, const u16* WtL, int K,
                   const float* alL, const float* arL,
                   const float* wr1, const float* wr2, const float* bL,
                   u16* outP, u16* outA, int relu) {
    if (K == 128) {
      gemm3<128><<<2 * nblkP + nblkA, 256, 0, stream>>>(
          inP, inA, WtL, fs0p, fs1a, fs2p, alL, arL,
          el0, el1, el2, er0, Np, Na, nblkP, nblkA);
    } else {
      gemm3<256><<<2 * nblkP + nblkA, 256, 0, stream>>>(
          inP, inA, WtL, fs0p, fs1a, fs2p, alL, arL,
          el0, el1, el2, er0, Np, Na, nblkP, nblkA);
    }
    er_wr2<<<cdiv(Np, 4) + cdiv(Na, 4), 256, 0, stream>>>(inP, inA, wr1, wr2, er1, er2, Np, Na, K);
    agg_paper<<<cdiv(Np, 4), 256, 0, stream>>>(rpC, srcsC, el0, er0, fs0p,
                                               rpW, srcsW, el1, er1, fs1a,
                                               bL, bL + 256, outP, Np, relu);
    agg_author<<<cdiv(Na, 4), 256, 0, stream>>>(rpR, srcsR, el2, er2, fs2p,
                                                bL + 512, outA, Na, relu);
  };

  layer(xpb, xab, Wt0, 128, al0, ar0, wr01, wr02, b0, h1p, h1a, 1);
  layer(h1p, h1a, Wt1, 256, al1, ar1, wr11, wr12, b1, h1p, h1a, 0);

  // ---- final linear ----
  gemm_rb<256, 3><<<dim3(cdiv(Np, 64)), 256, 0, stream>>>(
      h1p, Wtl, nullptr, out, linb, nullptr, nullptr, nullptr, nullptr, Np);
}